// Round 6
// baseline (635.218 us; speedup 1.0000x reference)
//
#include <hip/hip_runtime.h>
#include <math.h>

typedef __attribute__((ext_vector_type(8))) short bf16x8;
typedef __attribute__((ext_vector_type(4))) float f32x4;

#define DEV_INLINE __device__ __forceinline__

DEV_INLINE float silu_f(float v) { return v / (1.f + expf(-v)); }
DEV_INLINE float softplus_f(float v) { return (v > 20.f) ? v : log1pf(expf(v)); }
DEV_INLINE float b2f(unsigned short u) { return __uint_as_float(((unsigned int)u) << 16); }
DEV_INLINE unsigned short f2b(float f) {
  unsigned int u = __float_as_uint(f);
  return (unsigned short)((u + 0x7FFFu + ((u >> 16) & 1u)) >> 16);
}
DEV_INLINE void async16(const void* g, void* l) {
  __builtin_amdgcn_global_load_lds((const __attribute__((address_space(1))) unsigned int*)g,
                                   (__attribute__((address_space(3))) unsigned int*)l, 16, 0, 0);
}

// ---------------------------------------------------------------------------
// bf16 NT MFMA GEMM, double-buffered prefetch (2-phase pipeline):
// C[m,n] = act( sum_k A[m*lda+k]*B[n*ldb+k] + bias[n] )
// BM=BN=128, BK=32, 256 thr (4 waves 2x2), wave tile 64x64.
// LDS per buffer: row-major [128][32] bf16, slot swizzle c = s ^ ((row>>1)&3).
// XPROJ: N=68 logical; n<64 -> bf16 [m*64+n]; 64<=n<68 -> fp32 Cx[m*4+n-64].
// ---------------------------------------------------------------------------
template <int ACT, int HASBIAS, int XPROJ>
__global__ __launch_bounds__(256) void gemm_bf16_nt(
    const unsigned short* __restrict__ A, int lda,
    const unsigned short* __restrict__ B, int ldb,
    const float* __restrict__ bias,
    unsigned short* __restrict__ Cbf, int ldc,
    float* __restrict__ Cx, int K) {
  __shared__ unsigned short As[2][128 * 32];
  __shared__ unsigned short Bs[2][128 * 32];
  const int tid = threadIdx.x;
  const int w = tid >> 6, lane = tid & 63;
  const int bm = blockIdx.y * 128, bn = blockIdx.x * 128;
  const int wr = w >> 1, wc = w & 1;
  const int row0 = w * 16 + (lane >> 2);
  const int s_slot = lane & 3;

  int aoff[4], boff[4];
  const int cchunk = lane >> 4;
#pragma unroll
  for (int i = 0; i < 4; ++i) {
    int ra = wr * 64 + i * 16 + (lane & 15);
    aoff[i] = ra * 64 + ((cchunk ^ ((ra >> 1) & 3)) * 16);
    int rb = wc * 64 + i * 16 + (lane & 15);
    boff[i] = rb * 64 + ((cchunk ^ ((rb >> 1) & 3)) * 16);
  }

  // staging source offsets (k-invariant part)
  const int rowA0 = row0, rowA1 = row0 + 64;
  const int cA0 = s_slot ^ ((rowA0 >> 1) & 3);
  const int cA1 = s_slot ^ ((rowA1 >> 1) & 3);
  const unsigned short* gA0 = A + (size_t)(bm + rowA0) * lda + cA0 * 8;
  const unsigned short* gA1 = A + (size_t)(bm + rowA1) * lda + cA1 * 8;
  const unsigned short* gB0 = B + (size_t)(bn + rowA0) * ldb + cA0 * 8;
  const unsigned short* gB1 = B + (size_t)(bn + rowA1) * ldb + cA1 * 8;

  f32x4 acc[4][4];
#pragma unroll
  for (int i = 0; i < 4; ++i)
#pragma unroll
    for (int j = 0; j < 4; ++j) acc[i][j] = (f32x4){0.f, 0.f, 0.f, 0.f};

#define STAGE_NT(buf, k0)                                                  \
  do {                                                                     \
    async16(gA0 + (k0), (char*)As[buf] + w * 1024);                        \
    async16(gA1 + (k0), (char*)As[buf] + 4096 + w * 1024);                 \
    async16(gB0 + (k0), (char*)Bs[buf] + w * 1024);                        \
    async16(gB1 + (k0), (char*)Bs[buf] + 4096 + w * 1024);                 \
  } while (0)

  STAGE_NT(0, 0);
  __syncthreads();
  int cur = 0;
  for (int k0 = 0; k0 < K; k0 += 32) {
    if (k0 + 32 < K) STAGE_NT(cur ^ 1, k0 + 32);
    bf16x8 af[4], bf[4];
#pragma unroll
    for (int i = 0; i < 4; ++i) {
      af[i] = *(const bf16x8*)((const char*)As[cur] + aoff[i]);
      bf[i] = *(const bf16x8*)((const char*)Bs[cur] + boff[i]);
    }
#pragma unroll
    for (int i = 0; i < 4; ++i)
#pragma unroll
      for (int j = 0; j < 4; ++j)
        acc[i][j] = __builtin_amdgcn_mfma_f32_16x16x32_bf16(af[i], bf[j], acc[i][j], 0, 0, 0);
    __syncthreads();
    cur ^= 1;
  }
#undef STAGE_NT

#pragma unroll
  for (int i = 0; i < 4; ++i) {
#pragma unroll
    for (int j = 0; j < 4; ++j) {
      int ncol = bn + wc * 64 + j * 16 + (lane & 15);
      float bv = 0.f;
      if (HASBIAS) bv = bias[ncol];
#pragma unroll
      for (int r = 0; r < 4; ++r) {
        int mrow = bm + wr * 64 + i * 16 + (lane >> 4) * 4 + r;
        float v = acc[i][j][r] + bv;
        if (ACT == 1) v = silu_f(v);
        if (ACT == 2) v = softplus_f(v);
        if (XPROJ) {
          if (ncol < 64) Cbf[(size_t)mrow * 64 + ncol] = f2b(v);
          else if (ncol < 68) Cx[(size_t)mrow * 4 + (ncol - 64)] = v;
        } else {
          Cbf[(size_t)mrow * ldc + ncol] = f2b(v);
        }
      }
    }
  }
}

// ---------------------------------------------------------------------------
// Batched NT MFMA GEMM (shared weight A, per-batch B and C), double-buffered.
// C[b][m*ldc+n] = act( sum_k A[m*lda+k]*B[b][n*ldb+k] + bias[m] )
// ---------------------------------------------------------------------------
template <int ACT, int BIASM>
__global__ __launch_bounds__(256) void gemm_bf16_nt_bat(
    const unsigned short* __restrict__ A, int lda,
    const unsigned short* __restrict__ B, int ldb, size_t strideB,
    const float* __restrict__ bias,
    unsigned short* __restrict__ C, int ldc, size_t strideC, int K) {
  __shared__ unsigned short As[2][128 * 32];
  __shared__ unsigned short Bs[2][128 * 32];
  const int b = blockIdx.z;
  B += (size_t)b * strideB;
  C += (size_t)b * strideC;
  const int tid = threadIdx.x;
  const int w = tid >> 6, lane = tid & 63;
  const int bm = blockIdx.y * 128, bn = blockIdx.x * 128;
  const int wr = w >> 1, wc = w & 1;
  const int row0 = w * 16 + (lane >> 2);
  const int s_slot = lane & 3;

  int aoff[4], boff[4];
  const int cchunk = lane >> 4;
#pragma unroll
  for (int i = 0; i < 4; ++i) {
    int ra = wr * 64 + i * 16 + (lane & 15);
    aoff[i] = ra * 64 + ((cchunk ^ ((ra >> 1) & 3)) * 16);
    int rb = wc * 64 + i * 16 + (lane & 15);
    boff[i] = rb * 64 + ((cchunk ^ ((rb >> 1) & 3)) * 16);
  }

  const int rowA0 = row0, rowA1 = row0 + 64;
  const int cA0 = s_slot ^ ((rowA0 >> 1) & 3);
  const int cA1 = s_slot ^ ((rowA1 >> 1) & 3);
  const unsigned short* gA0 = A + (size_t)(bm + rowA0) * lda + cA0 * 8;
  const unsigned short* gA1 = A + (size_t)(bm + rowA1) * lda + cA1 * 8;
  const unsigned short* gB0 = B + (size_t)(bn + rowA0) * ldb + cA0 * 8;
  const unsigned short* gB1 = B + (size_t)(bn + rowA1) * ldb + cA1 * 8;

  f32x4 acc[4][4];
#pragma unroll
  for (int i = 0; i < 4; ++i)
#pragma unroll
    for (int j = 0; j < 4; ++j) acc[i][j] = (f32x4){0.f, 0.f, 0.f, 0.f};

#define STAGE_BAT(buf, k0)                                                 \
  do {                                                                     \
    async16(gA0 + (k0), (char*)As[buf] + w * 1024);                        \
    async16(gA1 + (k0), (char*)As[buf] + 4096 + w * 1024);                 \
    async16(gB0 + (k0), (char*)Bs[buf] + w * 1024);                        \
    async16(gB1 + (k0), (char*)Bs[buf] + 4096 + w * 1024);                 \
  } while (0)

  STAGE_BAT(0, 0);
  __syncthreads();
  int cur = 0;
  for (int k0 = 0; k0 < K; k0 += 32) {
    if (k0 + 32 < K) STAGE_BAT(cur ^ 1, k0 + 32);
    bf16x8 af[4], bf[4];
#pragma unroll
    for (int i = 0; i < 4; ++i) {
      af[i] = *(const bf16x8*)((const char*)As[cur] + aoff[i]);
      bf[i] = *(const bf16x8*)((const char*)Bs[cur] + boff[i]);
    }
#pragma unroll
    for (int i = 0; i < 4; ++i)
#pragma unroll
      for (int j = 0; j < 4; ++j)
        acc[i][j] = __builtin_amdgcn_mfma_f32_16x16x32_bf16(af[i], bf[j], acc[i][j], 0, 0, 0);
    __syncthreads();
    cur ^= 1;
  }
#undef STAGE_BAT

#pragma unroll
  for (int i = 0; i < 4; ++i) {
#pragma unroll
    for (int j = 0; j < 4; ++j) {
      int ncol = bn + wc * 64 + j * 16 + (lane & 15);
#pragma unroll
      for (int r = 0; r < 4; ++r) {
        int mrow = bm + wr * 64 + i * 16 + (lane >> 4) * 4 + r;
        float v = acc[i][j][r];
        if (BIASM) v += bias[mrow];
        if (ACT == 1) v = silu_f(v);
        C[(size_t)mrow * ldc + ncol] = f2b(v);
      }
    }
  }
}

// ---------------------------------------------------------------------------
// Final dual bf16 MFMA GEMM (batched, fp32 out), double-buffered.
// out[b][m*1024+n] = silu(W1[m,:]·Yt[b][n,:]+b1[m]) + silu(W2[m,:]·Rt[b][n,:]+b2[m])
// M=512, N=1024, K=512.
// ---------------------------------------------------------------------------
__global__ __launch_bounds__(256) void gemm_dual_mfma(
    const unsigned short* __restrict__ W1, const unsigned short* __restrict__ W2,
    const float* __restrict__ b1, const float* __restrict__ b2,
    const unsigned short* __restrict__ Yt, const unsigned short* __restrict__ Rt,
    float* __restrict__ out) {
  __shared__ unsigned short As1[2][128 * 32], As2[2][128 * 32];
  __shared__ unsigned short Bs1[2][128 * 32], Bs2[2][128 * 32];
  const int b = blockIdx.z;
  const unsigned short* Ytb = Yt + (size_t)b * 524288;
  const unsigned short* Rtb = Rt + (size_t)b * 524288;
  const int tid = threadIdx.x;
  const int w = tid >> 6, lane = tid & 63;
  const int bm = blockIdx.y * 128, bn = blockIdx.x * 128;
  const int wr = w >> 1, wc = w & 1;
  const int row0 = w * 16 + (lane >> 2);
  const int s_slot = lane & 3;

  int aoff[4], boff[4];
  const int cchunk = lane >> 4;
#pragma unroll
  for (int i = 0; i < 4; ++i) {
    int ra = wr * 64 + i * 16 + (lane & 15);
    aoff[i] = ra * 64 + ((cchunk ^ ((ra >> 1) & 3)) * 16);
    int rb = wc * 64 + i * 16 + (lane & 15);
    boff[i] = rb * 64 + ((cchunk ^ ((rb >> 1) & 3)) * 16);
  }

  const int rowA0 = row0, rowA1 = row0 + 64;
  const int cA0 = s_slot ^ ((rowA0 >> 1) & 3);
  const int cA1 = s_slot ^ ((rowA1 >> 1) & 3);
  const unsigned short* gW1a = W1 + (size_t)(bm + rowA0) * 512 + cA0 * 8;
  const unsigned short* gW1b = W1 + (size_t)(bm + rowA1) * 512 + cA1 * 8;
  const unsigned short* gW2a = W2 + (size_t)(bm + rowA0) * 512 + cA0 * 8;
  const unsigned short* gW2b = W2 + (size_t)(bm + rowA1) * 512 + cA1 * 8;
  const unsigned short* gYa = Ytb + (size_t)(bn + rowA0) * 512 + cA0 * 8;
  const unsigned short* gYb = Ytb + (size_t)(bn + rowA1) * 512 + cA1 * 8;
  const unsigned short* gRa = Rtb + (size_t)(bn + rowA0) * 512 + cA0 * 8;
  const unsigned short* gRb = Rtb + (size_t)(bn + rowA1) * 512 + cA1 * 8;

  f32x4 acc1[4][4], acc2[4][4];
#pragma unroll
  for (int i = 0; i < 4; ++i)
#pragma unroll
    for (int j = 0; j < 4; ++j) {
      acc1[i][j] = (f32x4){0.f, 0.f, 0.f, 0.f};
      acc2[i][j] = (f32x4){0.f, 0.f, 0.f, 0.f};
    }

#define STAGE_DUAL(buf, k0)                                                \
  do {                                                                     \
    async16(gW1a + (k0), (char*)As1[buf] + w * 1024);                      \
    async16(gW1b + (k0), (char*)As1[buf] + 4096 + w * 1024);               \
    async16(gW2a + (k0), (char*)As2[buf] + w * 1024);                      \
    async16(gW2b + (k0), (char*)As2[buf] + 4096 + w * 1024);               \
    async16(gYa + (k0), (char*)Bs1[buf] + w * 1024);                       \
    async16(gYb + (k0), (char*)Bs1[buf] + 4096 + w * 1024);                \
    async16(gRa + (k0), (char*)Bs2[buf] + w * 1024);                       \
    async16(gRb + (k0), (char*)Bs2[buf] + 4096 + w * 1024);                \
  } while (0)

  STAGE_DUAL(0, 0);
  __syncthreads();
  int cur = 0;
  for (int k0 = 0; k0 < 512; k0 += 32) {
    if (k0 + 32 < 512) STAGE_DUAL(cur ^ 1, k0 + 32);
    {
      bf16x8 af[4], bf[4];
#pragma unroll
      for (int i = 0; i < 4; ++i) {
        af[i] = *(const bf16x8*)((const char*)As1[cur] + aoff[i]);
        bf[i] = *(const bf16x8*)((const char*)Bs1[cur] + boff[i]);
      }
#pragma unroll
      for (int i = 0; i < 4; ++i)
#pragma unroll
        for (int j = 0; j < 4; ++j)
          acc1[i][j] = __builtin_amdgcn_mfma_f32_16x16x32_bf16(af[i], bf[j], acc1[i][j], 0, 0, 0);
    }
    {
      bf16x8 af[4], bf[4];
#pragma unroll
      for (int i = 0; i < 4; ++i) {
        af[i] = *(const bf16x8*)((const char*)As2[cur] + aoff[i]);
        bf[i] = *(const bf16x8*)((const char*)Bs2[cur] + boff[i]);
      }
#pragma unroll
      for (int i = 0; i < 4; ++i)
#pragma unroll
        for (int j = 0; j < 4; ++j)
          acc2[i][j] = __builtin_amdgcn_mfma_f32_16x16x32_bf16(af[i], bf[j], acc2[i][j], 0, 0, 0);
    }
    __syncthreads();
    cur ^= 1;
  }
#undef STAGE_DUAL

  float* outb = out + (size_t)b * 524288;
#pragma unroll
  for (int i = 0; i < 4; ++i) {
#pragma unroll
    for (int j = 0; j < 4; ++j) {
      int ncol = bn + wc * 64 + j * 16 + (lane & 15);
#pragma unroll
      for (int r = 0; r < 4; ++r) {
        int mrow = bm + wr * 64 + i * 16 + (lane >> 4) * 4 + r;
        float v = silu_f(acc1[i][j][r] + b1[mrow]) + silu_f(acc2[i][j][r] + b2[mrow]);
        outb[(size_t)mrow * 1024 + ncol] = v;
      }
    }
  }
}

// ---------------------------------------------------------------------------
__global__ __launch_bounds__(256) void cast_kernel(const float* __restrict__ in,
                                                   unsigned short* __restrict__ out, int n4) {
  int i = (blockIdx.x * 256 + threadIdx.x) * 4;
  if (i < n4) {
    float4 v = *(const float4*)(in + i);
    ushort4 o;
    o.x = f2b(v.x); o.y = f2b(v.y); o.z = f2b(v.z); o.w = f2b(v.w);
    *(ushort4*)(out + i) = o;
  }
}

__global__ __launch_bounds__(256) void cast_pad_xproj(const float* __restrict__ in,
                                                      unsigned short* __restrict__ out) {
  int i = (blockIdx.x * 256 + threadIdx.x) * 4;
  ushort4 o;
  if (i < 68 * 1024) {
    float4 v = *(const float4*)(in + i);
    o.x = f2b(v.x); o.y = f2b(v.y); o.z = f2b(v.z); o.w = f2b(v.w);
  } else {
    o.x = 0; o.y = 0; o.z = 0; o.w = 0;
  }
  *(ushort4*)(out + i) = o;
}

// ---------------------------------------------------------------------------
// Causal depthwise conv4 + bias + SiLU, bf16 in/out.
// in: row-stride instride (xz layout), out: [*1024].
// ---------------------------------------------------------------------------
__global__ __launch_bounds__(256) void conv_silu_bf16(
    const unsigned short* __restrict__ xin, int instride, const float* __restrict__ w,
    const float* __restrict__ cb, unsigned short* __restrict__ xout) {
  int idx = blockIdx.x * 256 + threadIdx.x;
  int d = idx & 1023;
  int l = (idx >> 10) & 511;
  int b = idx >> 19;
  const unsigned short* base = xin + ((size_t)b * 512) * instride + d;
  float acc = cb[d];
  float4 wv = *(const float4*)(w + d * 4);
  float wj[4] = {wv.x, wv.y, wv.z, wv.w};
#pragma unroll
  for (int j = 0; j < 4; ++j) {
    int ll = l - 3 + j;
    if (ll >= 0) acc = fmaf(wj[j], b2f(base[(size_t)ll * instride]), acc);
  }
  xout[idx] = f2b(silu_f(acc));
}

// ---------------------------------------------------------------------------
// Chunked selective scan (16 chunks of 32). delta/z have row-stride dzstride.
// ---------------------------------------------------------------------------
__global__ __launch_bounds__(1024) void scan_chunked(
    const unsigned short* __restrict__ delta, const unsigned short* __restrict__ z,
    int dzstride,
    const unsigned short* __restrict__ xs,
    const float* __restrict__ BC,
    const float* __restrict__ A_log, const float* __restrict__ D_ssm,
    unsigned short* __restrict__ yout) {
  __shared__ float4 ps[16][64];
  const int d_l = threadIdx.x & 63;
  const int ck = threadIdx.x >> 6;  // 0..15
  const int b = blockIdx.y;
  const int d = blockIdx.x * 64 + d_l;
  const float A0 = -expf(A_log[d * 2 + 0]);
  const float A1 = -expf(A_log[d * 2 + 1]);
  const size_t dzbase = ((size_t)b * 512 + ck * 32) * dzstride + d;
  const size_t base = ((size_t)b * 512 + ck * 32) * 1024 + d;
  const size_t bcb = ((size_t)b * 512 + ck * 32) * 4;

  float h0 = 0.f, h1 = 0.f, sumdl = 0.f;
  for (int i = 0; i < 32; ++i) {
    float dl = b2f(delta[dzbase + (size_t)i * dzstride]);
    float xv = b2f(xs[base + (size_t)i * 1024]);
    const float* q = BC + bcb + i * 4;
    sumdl += dl;
    float dx = dl * xv;
    h0 = fmaf(expf(dl * A0), h0, dx * q[0]);
    h1 = fmaf(expf(dl * A1), h1, dx * q[1]);
  }
  ps[ck][d_l] = make_float4(expf(A0 * sumdl), expf(A1 * sumdl), h0, h1);
  __syncthreads();

  h0 = 0.f; h1 = 0.f;
  for (int k = 0; k < ck; ++k) {
    float4 s = ps[k][d_l];
    h0 = fmaf(s.x, h0, s.z);
    h1 = fmaf(s.y, h1, s.w);
  }

  const float Dd = D_ssm[d];
  for (int i = 0; i < 32; ++i) {
    float dl = b2f(delta[dzbase + (size_t)i * dzstride]);
    size_t off = base + (size_t)i * 1024;
    float xv = b2f(xs[off]);
    const float* q = BC + bcb + i * 4;
    float dx = dl * xv;
    h0 = fmaf(expf(dl * A0), h0, dx * q[0]);
    h1 = fmaf(expf(dl * A1), h1, dx * q[1]);
    float y = fmaf(xv, Dd, fmaf(h0, q[2], h1 * q[3]));
    y *= silu_f(b2f(z[dzbase + (size_t)i * dzstride]));
    yout[off] = f2b(y);
  }
}

// ---------------------------------------------------------------------------
// Column LayerNorm on Yt[b][p][c] (stats over p per (b,c); g/bias indexed by p).
// ---------------------------------------------------------------------------
__global__ __launch_bounds__(256) void ln_col(unsigned short* __restrict__ Yt,
                                              const float* __restrict__ g,
                                              const float* __restrict__ be) {
  __shared__ float ps[4][64], ps2[4][64];
  const int b = blockIdx.y, cc = blockIdx.x * 64;
  const int cl = threadIdx.x & 63, pg = threadIdx.x >> 6;
  unsigned short* base = Yt + (size_t)b * 524288 + cc + cl;
  float s = 0.f, s2 = 0.f;
  const int p0 = pg * 256;
  for (int p = p0; p < p0 + 256; ++p) {
    float v = b2f(base[(size_t)p * 512]);
    s += v; s2 += v * v;
  }
  ps[pg][cl] = s; ps2[pg][cl] = s2;
  __syncthreads();
  float S = ps[0][cl] + ps[1][cl] + ps[2][cl] + ps[3][cl];
  float S2 = ps2[0][cl] + ps2[1][cl] + ps2[2][cl] + ps2[3][cl];
  float mu = S * (1.f / 1024.f);
  float var = S2 * (1.f / 1024.f) - mu * mu;
  float rstd = rsqrtf(var + 1e-5f);
  for (int p = p0; p < p0 + 256; ++p) {
    float v = b2f(base[(size_t)p * 512]);
    base[(size_t)p * 512] = f2b((v - mu) * rstd * g[p] + be[p]);
  }
}

// ---------------------------------------------------------------------------
extern "C" void kernel_launch(void* const* d_in, const int* in_sizes, int n_in,
                              void* d_out, int out_size, void* d_ws, size_t ws_size,
                              hipStream_t stream) {
  const float* x          = (const float*)d_in[0];
  const float* in_proj_w  = (const float*)d_in[1];
  const float* conv_w     = (const float*)d_in[2];
  const float* conv_b     = (const float*)d_in[3];
  const float* x_proj_w   = (const float*)d_in[4];
  const float* dt_proj_w  = (const float*)d_in[5];
  const float* dt_proj_b  = (const float*)d_in[6];
  const float* A_log      = (const float*)d_in[7];
  const float* D_ssm      = (const float*)d_in[8];
  const float* out_proj_w = (const float*)d_in[9];
  const float* ln_g       = (const float*)d_in[10];
  const float* ln_b       = (const float*)d_in[11];
  const float* lin3_w     = (const float*)d_in[12];
  const float* lin3_b     = (const float*)d_in[13];
  const float* linsp_w    = (const float*)d_in[14];
  const float* linsp_b    = (const float*)d_in[15];
  const float* linres_w   = (const float*)d_in[16];
  const float* linres_b   = (const float*)d_in[17];
  float* out = (float*)d_out;

  char* ws = (char*)d_ws;
  const size_t MB = 1024 * 1024;
  unsigned short* w_in_bf     = (unsigned short*)(ws + 0);                       // 4 MB
  unsigned short* w_out_bf    = (unsigned short*)(ws + 4 * MB);                  // 2 MB
  unsigned short* w_linsp_bf  = (unsigned short*)(ws + 6 * MB);                  // 2 MB
  unsigned short* w_xp_bf     = (unsigned short*)(ws + 8 * MB);                  // 256 KB
  unsigned short* w_dt_bf     = (unsigned short*)(ws + 8 * MB + 256 * 1024);     // 128 KB
  float*          BC          = (float*)(ws + 8 * MB + 384 * 1024);              // 128 KB
  unsigned short* dtA         = (unsigned short*)(ws + 8 * MB + 512 * 1024);     // 1 MB
  unsigned short* w_lin3_bf   = (unsigned short*)(ws + 10 * MB);                 // 512 KB
  unsigned short* w_linres_bf = (unsigned short*)(ws + 10 * MB + 512 * 1024);    // 512 KB
  unsigned short* x_bf  = (unsigned short*)(ws + 16 * MB);  // 16 MB
  unsigned short* xz    = (unsigned short*)(ws + 32 * MB);  // 32 MB: [8192][2048] xs_pre|z; cols 0-1023 -> delta; later Rt
  unsigned short* seg3  = (unsigned short*)(ws + 64 * MB);  // 16 MB: xs -> Yt
  unsigned short* seg4  = (unsigned short*)(ws + 80 * MB);  // 16 MB: y_gated

  dim3 blk(256);
  // casts
  cast_kernel<<<2048, blk, 0, stream>>>(in_proj_w, w_in_bf, 2048 * 1024);
  cast_kernel<<<1024, blk, 0, stream>>>(out_proj_w, w_out_bf, 1024 * 1024);
  cast_kernel<<<1024, blk, 0, stream>>>(linsp_w, w_linsp_bf, 1024 * 1024);
  cast_pad_xproj<<<128, blk, 0, stream>>>(x_proj_w, w_xp_bf);
  cast_kernel<<<64, blk, 0, stream>>>(dt_proj_w, w_dt_bf, 1024 * 64);
  cast_kernel<<<256, blk, 0, stream>>>(lin3_w, w_lin3_bf, 512 * 512);
  cast_kernel<<<256, blk, 0, stream>>>(linres_w, w_linres_bf, 512 * 512);
  cast_kernel<<<8192, blk, 0, stream>>>(x, x_bf, 8192 * 1024);

  // in_proj merged: N=2048 -> xz[m][0:1024]=xs_pre, [1024:2048]=z
  gemm_bf16_nt<0, 0, 0><<<dim3(16, 64), blk, 0, stream>>>(
      x_bf, 1024, w_in_bf, 1024, nullptr, xz, 2048, nullptr, 1024);
  // conv + silu -> xs (seg3)
  conv_silu_bf16<<<32768, blk, 0, stream>>>(xz, 2048, conv_w, conv_b, seg3);
  // x_proj -> dtA (bf16) + BC (fp32)
  gemm_bf16_nt<0, 0, 1><<<dim3(1, 64), blk, 0, stream>>>(
      seg3, 1024, w_xp_bf, 1024, nullptr, dtA, 64, BC, 1024);
  // dt_proj + bias + softplus -> delta (into xz cols 0-1023; xs_pre is dead)
  gemm_bf16_nt<2, 1, 0><<<dim3(8, 64), blk, 0, stream>>>(
      dtA, 64, w_dt_bf, 64, dt_proj_b, xz, 2048, nullptr, 64);
  // chunked scan -> y_gated (seg4); delta & z read from xz (stride 2048)
  scan_chunked<<<dim3(16, 16), dim3(1024), 0, stream>>>(
      xz, xz + 1024, 2048, seg3, BC, A_log, D_ssm, seg4);
  // out_proj, per-batch transposed: Yt[b][p][c] -> seg3 (xs dead)
  gemm_bf16_nt_bat<0, 0><<<dim3(4, 8, 16), blk, 0, stream>>>(
      w_out_bf, 1024, seg4, 1024, 524288, nullptr, seg3, 512, 524288, 1024);
  // column LayerNorm on Yt
  ln_col<<<dim3(8, 16), blk, 0, stream>>>(seg3, ln_g, ln_b);
  // linsp, per-batch transposed: Rt[b][p][c] -> xz region (delta/z dead)
  gemm_bf16_nt_bat<1, 1><<<dim3(4, 8, 16), blk, 0, stream>>>(
      w_linsp_bf, 1024, x_bf, 1024, 524288, linsp_b, xz, 512, 524288, 1024);
  // fused final dual MFMA
  gemm_dual_mfma<<<dim3(8, 4, 16), blk, 0, stream>>>(
      w_lin3_bf, w_linres_bf, lin3_b, linres_b, seg3, xz, out);
}

// Round 7
// 483.106 us; speedup vs baseline: 1.3149x; 1.3149x over previous
//
#include <hip/hip_runtime.h>
#include <math.h>

typedef __attribute__((ext_vector_type(8))) short bf16x8;
typedef __attribute__((ext_vector_type(4))) float f32x4;

#define DEV_INLINE __device__ __forceinline__

DEV_INLINE float silu_f(float v) { return v / (1.f + expf(-v)); }
DEV_INLINE float softplus_f(float v) { return (v > 20.f) ? v : log1pf(expf(v)); }
DEV_INLINE float b2f(unsigned short u) { return __uint_as_float(((unsigned int)u) << 16); }
DEV_INLINE unsigned short f2b(float f) {
  unsigned int u = __float_as_uint(f);
  return (unsigned short)((u + 0x7FFFu + ((u >> 16) & 1u)) >> 16);
}
DEV_INLINE void async16(const void* g, void* l) {
  __builtin_amdgcn_global_load_lds((const __attribute__((address_space(1))) unsigned int*)g,
                                   (__attribute__((address_space(3))) unsigned int*)l, 16, 0, 0);
}

// ---------------------------------------------------------------------------
// bf16 NT MFMA GEMM (single-buffered, proven round-5 structure):
// C[m,n] = act( sum_k A[m*lda+k]*B[n*ldb+k] + bias[n] )
// BM=BN=128, BK=32, 256 thr (4 waves 2x2), wave tile 64x64.
// LDS: row-major [128][32] bf16, slot swizzle c = s ^ ((row>>1)&3).
// NOTE: explicit double-buffering REGRESSED (r6: compiler inserts vmcnt(0)
// before ds_read, serializing the prefetch). Keep this 2-barrier form.
// ---------------------------------------------------------------------------
template <int ACT, int HASBIAS>
__global__ __launch_bounds__(256) void gemm_bf16_nt(
    const unsigned short* __restrict__ A, int lda,
    const unsigned short* __restrict__ B, int ldb,
    const float* __restrict__ bias,
    unsigned short* __restrict__ Cbf, int ldc, int K) {
  __shared__ unsigned short As[128 * 32];
  __shared__ unsigned short Bs[128 * 32];
  const int tid = threadIdx.x;
  const int w = tid >> 6, lane = tid & 63;
  const int bm = blockIdx.y * 128, bn = blockIdx.x * 128;
  const int wr = w >> 1, wc = w & 1;
  const int row0 = w * 16 + (lane >> 2);
  const int s_slot = lane & 3;

  int aoff[4], boff[4];
  const int cchunk = lane >> 4;
#pragma unroll
  for (int i = 0; i < 4; ++i) {
    int ra = wr * 64 + i * 16 + (lane & 15);
    aoff[i] = ra * 64 + ((cchunk ^ ((ra >> 1) & 3)) * 16);
    int rb = wc * 64 + i * 16 + (lane & 15);
    boff[i] = rb * 64 + ((cchunk ^ ((rb >> 1) & 3)) * 16);
  }

  f32x4 acc[4][4];
#pragma unroll
  for (int i = 0; i < 4; ++i)
#pragma unroll
    for (int j = 0; j < 4; ++j) acc[i][j] = (f32x4){0.f, 0.f, 0.f, 0.f};

  for (int k0 = 0; k0 < K; k0 += 32) {
#pragma unroll
    for (int u = 0; u < 2; ++u) {
      int row = row0 + u * 64;
      int c = s_slot ^ ((row >> 1) & 3);
      async16(A + (size_t)(bm + row) * lda + k0 + c * 8, (char*)As + u * 4096 + w * 1024);
      async16(B + (size_t)(bn + row) * ldb + k0 + c * 8, (char*)Bs + u * 4096 + w * 1024);
    }
    __syncthreads();
    bf16x8 af[4], bf[4];
#pragma unroll
    for (int i = 0; i < 4; ++i) {
      af[i] = *(const bf16x8*)((const char*)As + aoff[i]);
      bf[i] = *(const bf16x8*)((const char*)Bs + boff[i]);
    }
#pragma unroll
    for (int i = 0; i < 4; ++i)
#pragma unroll
      for (int j = 0; j < 4; ++j)
        acc[i][j] = __builtin_amdgcn_mfma_f32_16x16x32_bf16(af[i], bf[j], acc[i][j], 0, 0, 0);
    __syncthreads();
  }

#pragma unroll
  for (int i = 0; i < 4; ++i) {
#pragma unroll
    for (int j = 0; j < 4; ++j) {
      int ncol = bn + wc * 64 + j * 16 + (lane & 15);
      float bv = 0.f;
      if (HASBIAS) bv = bias[ncol];
#pragma unroll
      for (int r = 0; r < 4; ++r) {
        int mrow = bm + wr * 64 + i * 16 + (lane >> 4) * 4 + r;
        float v = acc[i][j][r] + bv;
        if (ACT == 1) v = silu_f(v);
        if (ACT == 2) v = softplus_f(v);
        Cbf[(size_t)mrow * ldc + ncol] = f2b(v);
      }
    }
  }
}

// ---------------------------------------------------------------------------
// Batched NT MFMA GEMM (shared weight A, per-batch B and C), bias per-M, bf16 out.
// ---------------------------------------------------------------------------
template <int ACT, int BIASM>
__global__ __launch_bounds__(256) void gemm_bf16_nt_bat(
    const unsigned short* __restrict__ A, int lda,
    const unsigned short* __restrict__ B, int ldb, size_t strideB,
    const float* __restrict__ bias,
    unsigned short* __restrict__ C, int ldc, size_t strideC, int K) {
  __shared__ unsigned short As[128 * 32];
  __shared__ unsigned short Bs[128 * 32];
  const int b = blockIdx.z;
  B += (size_t)b * strideB;
  C += (size_t)b * strideC;
  const int tid = threadIdx.x;
  const int w = tid >> 6, lane = tid & 63;
  const int bm = blockIdx.y * 128, bn = blockIdx.x * 128;
  const int wr = w >> 1, wc = w & 1;
  const int row0 = w * 16 + (lane >> 2);
  const int s_slot = lane & 3;

  int aoff[4], boff[4];
  const int cchunk = lane >> 4;
#pragma unroll
  for (int i = 0; i < 4; ++i) {
    int ra = wr * 64 + i * 16 + (lane & 15);
    aoff[i] = ra * 64 + ((cchunk ^ ((ra >> 1) & 3)) * 16);
    int rb = wc * 64 + i * 16 + (lane & 15);
    boff[i] = rb * 64 + ((cchunk ^ ((rb >> 1) & 3)) * 16);
  }

  f32x4 acc[4][4];
#pragma unroll
  for (int i = 0; i < 4; ++i)
#pragma unroll
    for (int j = 0; j < 4; ++j) acc[i][j] = (f32x4){0.f, 0.f, 0.f, 0.f};

  for (int k0 = 0; k0 < K; k0 += 32) {
#pragma unroll
    for (int u = 0; u < 2; ++u) {
      int row = row0 + u * 64;
      int c = s_slot ^ ((row >> 1) & 3);
      async16(A + (size_t)(bm + row) * lda + k0 + c * 8, (char*)As + u * 4096 + w * 1024);
      async16(B + (size_t)(bn + row) * ldb + k0 + c * 8, (char*)Bs + u * 4096 + w * 1024);
    }
    __syncthreads();
    bf16x8 af[4], bf[4];
#pragma unroll
    for (int i = 0; i < 4; ++i) {
      af[i] = *(const bf16x8*)((const char*)As + aoff[i]);
      bf[i] = *(const bf16x8*)((const char*)Bs + boff[i]);
    }
#pragma unroll
    for (int i = 0; i < 4; ++i)
#pragma unroll
      for (int j = 0; j < 4; ++j)
        acc[i][j] = __builtin_amdgcn_mfma_f32_16x16x32_bf16(af[i], bf[j], acc[i][j], 0, 0, 0);
    __syncthreads();
  }

#pragma unroll
  for (int i = 0; i < 4; ++i) {
#pragma unroll
    for (int j = 0; j < 4; ++j) {
      int ncol = bn + wc * 64 + j * 16 + (lane & 15);
#pragma unroll
      for (int r = 0; r < 4; ++r) {
        int mrow = bm + wr * 64 + i * 16 + (lane >> 4) * 4 + r;
        float v = acc[i][j][r];
        if (BIASM) v += bias[mrow];
        if (ACT == 1) v = silu_f(v);
        C[(size_t)mrow * ldc + ncol] = f2b(v);
      }
    }
  }
}

// ---------------------------------------------------------------------------
// Final dual bf16 MFMA GEMM (batched, fp32 out), single-buffered.
// ---------------------------------------------------------------------------
__global__ __launch_bounds__(256) void gemm_dual_mfma(
    const unsigned short* __restrict__ W1, const unsigned short* __restrict__ W2,
    const float* __restrict__ b1, const float* __restrict__ b2,
    const unsigned short* __restrict__ Yt, const unsigned short* __restrict__ Rt,
    float* __restrict__ out) {
  __shared__ unsigned short As1[128 * 32], As2[128 * 32];
  __shared__ unsigned short Bs1[128 * 32], Bs2[128 * 32];
  const int b = blockIdx.z;
  const unsigned short* Ytb = Yt + (size_t)b * 524288;
  const unsigned short* Rtb = Rt + (size_t)b * 524288;
  const int tid = threadIdx.x;
  const int w = tid >> 6, lane = tid & 63;
  const int bm = blockIdx.y * 128, bn = blockIdx.x * 128;
  const int wr = w >> 1, wc = w & 1;
  const int row0 = w * 16 + (lane >> 2);
  const int s_slot = lane & 3;

  int aoff[4], boff[4];
  const int cchunk = lane >> 4;
#pragma unroll
  for (int i = 0; i < 4; ++i) {
    int ra = wr * 64 + i * 16 + (lane & 15);
    aoff[i] = ra * 64 + ((cchunk ^ ((ra >> 1) & 3)) * 16);
    int rb = wc * 64 + i * 16 + (lane & 15);
    boff[i] = rb * 64 + ((cchunk ^ ((rb >> 1) & 3)) * 16);
  }

  f32x4 acc1[4][4], acc2[4][4];
#pragma unroll
  for (int i = 0; i < 4; ++i)
#pragma unroll
    for (int j = 0; j < 4; ++j) {
      acc1[i][j] = (f32x4){0.f, 0.f, 0.f, 0.f};
      acc2[i][j] = (f32x4){0.f, 0.f, 0.f, 0.f};
    }

  for (int k0 = 0; k0 < 512; k0 += 32) {
#pragma unroll
    for (int u = 0; u < 2; ++u) {
      int row = row0 + u * 64;
      int c = s_slot ^ ((row >> 1) & 3);
      async16(W1 + (size_t)(bm + row) * 512 + k0 + c * 8, (char*)As1 + u * 4096 + w * 1024);
      async16(W2 + (size_t)(bm + row) * 512 + k0 + c * 8, (char*)As2 + u * 4096 + w * 1024);
      async16(Ytb + (size_t)(bn + row) * 512 + k0 + c * 8, (char*)Bs1 + u * 4096 + w * 1024);
      async16(Rtb + (size_t)(bn + row) * 512 + k0 + c * 8, (char*)Bs2 + u * 4096 + w * 1024);
    }
    __syncthreads();
    {
      bf16x8 af[4], bf[4];
#pragma unroll
      for (int i = 0; i < 4; ++i) {
        af[i] = *(const bf16x8*)((const char*)As1 + aoff[i]);
        bf[i] = *(const bf16x8*)((const char*)Bs1 + boff[i]);
      }
#pragma unroll
      for (int i = 0; i < 4; ++i)
#pragma unroll
        for (int j = 0; j < 4; ++j)
          acc1[i][j] = __builtin_amdgcn_mfma_f32_16x16x32_bf16(af[i], bf[j], acc1[i][j], 0, 0, 0);
    }
    {
      bf16x8 af[4], bf[4];
#pragma unroll
      for (int i = 0; i < 4; ++i) {
        af[i] = *(const bf16x8*)((const char*)As2 + aoff[i]);
        bf[i] = *(const bf16x8*)((const char*)Bs2 + boff[i]);
      }
#pragma unroll
      for (int i = 0; i < 4; ++i)
#pragma unroll
        for (int j = 0; j < 4; ++j)
          acc2[i][j] = __builtin_amdgcn_mfma_f32_16x16x32_bf16(af[i], bf[j], acc2[i][j], 0, 0, 0);
    }
    __syncthreads();
  }

  float* outb = out + (size_t)b * 524288;
#pragma unroll
  for (int i = 0; i < 4; ++i) {
#pragma unroll
    for (int j = 0; j < 4; ++j) {
      int ncol = bn + wc * 64 + j * 16 + (lane & 15);
#pragma unroll
      for (int r = 0; r < 4; ++r) {
        int mrow = bm + wr * 64 + i * 16 + (lane >> 4) * 4 + r;
        float v = silu_f(acc1[i][j][r] + b1[mrow]) + silu_f(acc2[i][j][r] + b2[mrow]);
        outb[(size_t)mrow * 1024 + ncol] = v;
      }
    }
  }
}

// ---------------------------------------------------------------------------
__global__ __launch_bounds__(256) void cast_kernel(const float* __restrict__ in,
                                                   unsigned short* __restrict__ out, int n4) {
  int i = (blockIdx.x * 256 + threadIdx.x) * 4;
  if (i < n4) {
    float4 v = *(const float4*)(in + i);
    ushort4 o;
    o.x = f2b(v.x); o.y = f2b(v.y); o.z = f2b(v.z); o.w = f2b(v.w);
    *(ushort4*)(out + i) = o;
  }
}

// Transpose-cast x_proj_w rows 0..63 -> xpT[k*64+r] = xp[r*1024+k], bf16.
__global__ __launch_bounds__(256) void transpose_cast_xp(const float* __restrict__ in,
                                                         unsigned short* __restrict__ out) {
  int idx = blockIdx.x * 256 + threadIdx.x;  // 65536 total
  int k = idx >> 6;
  int r = idx & 63;
  out[idx] = f2b(in[r * 1024 + k]);
}

// ---------------------------------------------------------------------------
// BC[m][j] = sum_k xs[m][k] * x_proj_w[64+j][k], j=0..3 (fp32 weights, L1-hot).
// One wave per row m; grid 2048 x 256 thr (4 waves).
// ---------------------------------------------------------------------------
__global__ __launch_bounds__(256) void bc_kernel(
    const unsigned short* __restrict__ xs, const float* __restrict__ xp_w,
    float* __restrict__ BC) {
  const int wave = threadIdx.x >> 6, lane = threadIdx.x & 63;
  const int m = blockIdx.x * 4 + wave;
  const unsigned short* row = xs + (size_t)m * 1024;
  const float* w0 = xp_w + 64 * 1024;
  float s0 = 0.f, s1 = 0.f, s2 = 0.f, s3 = 0.f;
#pragma unroll
  for (int e = 0; e < 16; ++e) {
    int k = lane + e * 64;
    float xv = b2f(row[k]);
    s0 = fmaf(xv, w0[k], s0);
    s1 = fmaf(xv, w0[1024 + k], s1);
    s2 = fmaf(xv, w0[2048 + k], s2);
    s3 = fmaf(xv, w0[3072 + k], s3);
  }
#pragma unroll
  for (int off = 32; off > 0; off >>= 1) {
    s0 += __shfl_down(s0, off);
    s1 += __shfl_down(s1, off);
    s2 += __shfl_down(s2, off);
    s3 += __shfl_down(s3, off);
  }
  if (lane == 0) *(float4*)(BC + (size_t)m * 4) = make_float4(s0, s1, s2, s3);
}

// ---------------------------------------------------------------------------
// Causal depthwise conv4 + bias + SiLU, bf16 in/out. Layout [(b*512+l)*1024+d].
// ---------------------------------------------------------------------------
__global__ __launch_bounds__(256) void conv_silu_bf16(
    const unsigned short* __restrict__ xin, const float* __restrict__ w,
    const float* __restrict__ cb, unsigned short* __restrict__ xout) {
  int idx = blockIdx.x * 256 + threadIdx.x;
  int d = idx & 1023;
  int l = (idx >> 10) & 511;
  int b = idx >> 19;
  const unsigned short* base = xin + ((size_t)b * 512) * 1024 + d;
  float acc = cb[d];
  float4 wv = *(const float4*)(w + d * 4);
  float wj[4] = {wv.x, wv.y, wv.z, wv.w};
#pragma unroll
  for (int j = 0; j < 4; ++j) {
    int ll = l - 3 + j;
    if (ll >= 0) acc = fmaf(wj[j], b2f(base[(size_t)ll * 1024]), acc);
  }
  xout[idx] = f2b(silu_f(acc));
}

// ---------------------------------------------------------------------------
// Chunked selective scan: 16 chunks of 32, block = 1024 thr (64 d x 16 chunks).
// ---------------------------------------------------------------------------
__global__ __launch_bounds__(1024) void scan_chunked(
    const unsigned short* __restrict__ delta, const unsigned short* __restrict__ xs,
    const float* __restrict__ BC, const unsigned short* __restrict__ z,
    const float* __restrict__ A_log, const float* __restrict__ D_ssm,
    unsigned short* __restrict__ yout) {
  __shared__ float4 ps[16][64];
  const int d_l = threadIdx.x & 63;
  const int ck = threadIdx.x >> 6;
  const int b = blockIdx.y;
  const int d = blockIdx.x * 64 + d_l;
  const float A0 = -expf(A_log[d * 2 + 0]);
  const float A1 = -expf(A_log[d * 2 + 1]);
  const size_t base = ((size_t)b * 512 + ck * 32) * 1024 + d;
  const size_t bcb = ((size_t)b * 512 + ck * 32) * 4;

  float h0 = 0.f, h1 = 0.f, sumdl = 0.f;
  for (int i = 0; i < 32; ++i) {
    size_t off = base + (size_t)i * 1024;
    float dl = b2f(delta[off]);
    float xv = b2f(xs[off]);
    const float* q = BC + bcb + i * 4;
    sumdl += dl;
    float dx = dl * xv;
    h0 = fmaf(expf(dl * A0), h0, dx * q[0]);
    h1 = fmaf(expf(dl * A1), h1, dx * q[1]);
  }
  ps[ck][d_l] = make_float4(expf(A0 * sumdl), expf(A1 * sumdl), h0, h1);
  __syncthreads();

  h0 = 0.f; h1 = 0.f;
  for (int k = 0; k < ck; ++k) {
    float4 s = ps[k][d_l];
    h0 = fmaf(s.x, h0, s.z);
    h1 = fmaf(s.y, h1, s.w);
  }

  const float Dd = D_ssm[d];
  for (int i = 0; i < 32; ++i) {
    size_t off = base + (size_t)i * 1024;
    float dl = b2f(delta[off]);
    float xv = b2f(xs[off]);
    const float* q = BC + bcb + i * 4;
    float dx = dl * xv;
    h0 = fmaf(expf(dl * A0), h0, dx * q[0]);
    h1 = fmaf(expf(dl * A1), h1, dx * q[1]);
    float y = fmaf(xv, Dd, fmaf(h0, q[2], h1 * q[3]));
    y *= silu_f(b2f(z[off]));
    yout[off] = f2b(y);
  }
}

// ---------------------------------------------------------------------------
// Column LayerNorm on Yt[b][p][c] (stats over p per (b,c); g/bias indexed by p).
// ---------------------------------------------------------------------------
__global__ __launch_bounds__(256) void ln_col(unsigned short* __restrict__ Yt,
                                              const float* __restrict__ g,
                                              const float* __restrict__ be) {
  __shared__ float ps[4][64], ps2[4][64];
  const int b = blockIdx.y, cc = blockIdx.x * 64;
  const int cl = threadIdx.x & 63, pg = threadIdx.x >> 6;
  unsigned short* base = Yt + (size_t)b * 524288 + cc + cl;
  float s = 0.f, s2 = 0.f;
  const int p0 = pg * 256;
  for (int p = p0; p < p0 + 256; ++p) {
    float v = b2f(base[(size_t)p * 512]);
    s += v; s2 += v * v;
  }
  ps[pg][cl] = s; ps2[pg][cl] = s2;
  __syncthreads();
  float S = ps[0][cl] + ps[1][cl] + ps[2][cl] + ps[3][cl];
  float S2 = ps2[0][cl] + ps2[1][cl] + ps2[2][cl] + ps2[3][cl];
  float mu = S * (1.f / 1024.f);
  float var = S2 * (1.f / 1024.f) - mu * mu;
  float rstd = rsqrtf(var + 1e-5f);
  for (int p = p0; p < p0 + 256; ++p) {
    float v = b2f(base[(size_t)p * 512]);
    base[(size_t)p * 512] = f2b((v - mu) * rstd * g[p] + be[p]);
  }
}

// ---------------------------------------------------------------------------
extern "C" void kernel_launch(void* const* d_in, const int* in_sizes, int n_in,
                              void* d_out, int out_size, void* d_ws, size_t ws_size,
                              hipStream_t stream) {
  const float* x          = (const float*)d_in[0];
  const float* in_proj_w  = (const float*)d_in[1];
  const float* conv_w     = (const float*)d_in[2];
  const float* conv_b     = (const float*)d_in[3];
  const float* x_proj_w   = (const float*)d_in[4];
  const float* dt_proj_w  = (const float*)d_in[5];
  const float* dt_proj_b  = (const float*)d_in[6];
  const float* A_log      = (const float*)d_in[7];
  const float* D_ssm      = (const float*)d_in[8];
  const float* out_proj_w = (const float*)d_in[9];
  const float* ln_g       = (const float*)d_in[10];
  const float* ln_b       = (const float*)d_in[11];
  const float* lin3_w     = (const float*)d_in[12];
  const float* lin3_b     = (const float*)d_in[13];
  const float* linsp_w    = (const float*)d_in[14];
  const float* linsp_b    = (const float*)d_in[15];
  const float* linres_w   = (const float*)d_in[16];
  const float* linres_b   = (const float*)d_in[17];
  float* out = (float*)d_out;

  char* ws = (char*)d_ws;
  const size_t MB = 1024 * 1024;
  unsigned short* w_in_bf     = (unsigned short*)(ws + 0);                     // 4 MB
  unsigned short* w_out_bf    = (unsigned short*)(ws + 4 * MB);                // 2 MB
  unsigned short* w_linsp_bf  = (unsigned short*)(ws + 6 * MB);                // 2 MB
  unsigned short* w_dt_bf     = (unsigned short*)(ws + 8 * MB);                // 128 KB (1024x64)
  unsigned short* xpT_bf      = (unsigned short*)(ws + 8 * MB + 128 * 1024);   // 128 KB (1024x64)
  float*          BC          = (float*)(ws + 8 * MB + 256 * 1024);            // 128 KB
  unsigned short* W_eff       = (unsigned short*)(ws + 9 * MB);                // 2 MB (1024x1024)
  unsigned short* w_lin3_bf   = (unsigned short*)(ws + 11 * MB);               // 512 KB
  unsigned short* w_linres_bf = (unsigned short*)(ws + 11 * MB + 512 * 1024);  // 512 KB
  unsigned short* x_bf  = (unsigned short*)(ws + 16 * MB);  // 16 MB
  unsigned short* seg1  = (unsigned short*)(ws + 32 * MB);  // xs_pre -> delta -> Yt
  unsigned short* seg2  = (unsigned short*)(ws + 48 * MB);  // z -> Rt
  unsigned short* seg3  = (unsigned short*)(ws + 64 * MB);  // xs
  unsigned short* seg4  = (unsigned short*)(ws + 80 * MB);  // y_gated

  dim3 blk(256);
  // casts
  cast_kernel<<<2048, blk, 0, stream>>>(in_proj_w, w_in_bf, 2048 * 1024);
  cast_kernel<<<1024, blk, 0, stream>>>(out_proj_w, w_out_bf, 1024 * 1024);
  cast_kernel<<<1024, blk, 0, stream>>>(linsp_w, w_linsp_bf, 1024 * 1024);
  cast_kernel<<<64, blk, 0, stream>>>(dt_proj_w, w_dt_bf, 1024 * 64);
  transpose_cast_xp<<<256, blk, 0, stream>>>(x_proj_w, xpT_bf);
  cast_kernel<<<256, blk, 0, stream>>>(lin3_w, w_lin3_bf, 512 * 512);
  cast_kernel<<<256, blk, 0, stream>>>(linres_w, w_linres_bf, 512 * 512);
  cast_kernel<<<8192, blk, 0, stream>>>(x, x_bf, 8192 * 1024);

  // W_eff = dt_proj_w @ x_proj_w[0:64]  (M=1024, N=1024, K=64)
  gemm_bf16_nt<0, 0><<<dim3(8, 8), blk, 0, stream>>>(
      w_dt_bf, 64, xpT_bf, 64, nullptr, W_eff, 1024, 64);

  // in_proj (xs_pre -> seg1, z -> seg2)
  gemm_bf16_nt<0, 0><<<dim3(8, 64), blk, 0, stream>>>(
      x_bf, 1024, w_in_bf, 1024, nullptr, seg1, 1024, 1024);
  gemm_bf16_nt<0, 0><<<dim3(8, 64), blk, 0, stream>>>(
      x_bf, 1024, w_in_bf + (size_t)1024 * 1024, 1024, nullptr, seg2, 1024, 1024);
  // conv + silu -> xs (seg3)
  conv_silu_bf16<<<32768, blk, 0, stream>>>(seg1, conv_w, conv_b, seg3);
  // BC = xs . x_proj_w[64:68]^T  (fp32)
  bc_kernel<<<2048, blk, 0, stream>>>(seg3, x_proj_w, BC);
  // delta = softplus(xs . W_eff^T + dt_proj_b) -> seg1
  gemm_bf16_nt<2, 1><<<dim3(8, 64), blk, 0, stream>>>(
      seg3, 1024, W_eff, 1024, dt_proj_b, seg1, 1024, 1024);
  // chunked scan -> y_gated (seg4)
  scan_chunked<<<dim3(16, 16), dim3(1024), 0, stream>>>(
      seg1, seg3, BC, seg2, A_log, D_ssm, seg4);
  // out_proj, per-batch transposed: Yt[b][p][c] -> seg1
  gemm_bf16_nt_bat<0, 0><<<dim3(4, 8, 16), blk, 0, stream>>>(
      w_out_bf, 1024, seg4, 1024, 524288, nullptr, seg1, 512, 524288, 1024);
  // column LayerNorm on Yt
  ln_col<<<dim3(8, 16), blk, 0, stream>>>(seg1, ln_g, ln_b);
  // linsp, per-batch transposed: Rt[b][p][c] = silu(W_sp.x + b[p]) -> seg2
  gemm_bf16_nt_bat<1, 1><<<dim3(4, 8, 16), blk, 0, stream>>>(
      w_linsp_bf, 1024, x_bf, 1024, 524288, linsp_b, seg2, 512, 524288, 1024);
  // fused final dual MFMA
  gemm_dual_mfma<<<dim3(8, 4, 16), blk, 0, stream>>>(
      w_lin3_bf, w_linres_bf, lin3_b, linres_b, seg1, seg2, out);
}

// Round 8
// 471.685 us; speedup vs baseline: 1.3467x; 1.0242x over previous
//
#include <hip/hip_runtime.h>
#include <math.h>

typedef __attribute__((ext_vector_type(8))) short bf16x8;
typedef __attribute__((ext_vector_type(4))) float f32x4;

#define DEV_INLINE __device__ __forceinline__

DEV_INLINE float silu_f(float v) { return v / (1.f + expf(-v)); }
DEV_INLINE float softplus_f(float v) { return (v > 20.f) ? v : log1pf(expf(v)); }
DEV_INLINE float b2f(unsigned short u) { return __uint_as_float(((unsigned int)u) << 16); }
DEV_INLINE unsigned short f2b(float f) {
  unsigned int u = __float_as_uint(f);
  return (unsigned short)((u + 0x7FFFu + ((u >> 16) & 1u)) >> 16);
}
DEV_INLINE void async16(const void* g, void* l) {
  __builtin_amdgcn_global_load_lds((const __attribute__((address_space(1))) unsigned int*)g,
                                   (__attribute__((address_space(3))) unsigned int*)l, 16, 0, 0);
}

// ---------------------------------------------------------------------------
// bf16 NT MFMA GEMM (single-buffered, proven structure — do NOT hand-pipeline;
// r6 showed compiler serializes explicit dbuf with vmcnt(0) before ds_read):
// C[m,n] = act( sum_k A[m*lda+k]*B[n*ldb+k] + bias[n] )
// BM=BN=128, BK=32, 256 thr (4 waves 2x2), wave tile 64x64.
// LDS: row-major [128][32] bf16, slot swizzle c = s ^ ((row>>1)&3).
// ---------------------------------------------------------------------------
template <int ACT, int HASBIAS>
__global__ __launch_bounds__(256) void gemm_bf16_nt(
    const unsigned short* __restrict__ A, int lda,
    const unsigned short* __restrict__ B, int ldb,
    const float* __restrict__ bias,
    unsigned short* __restrict__ Cbf, int ldc, int K) {
  __shared__ unsigned short As[128 * 32];
  __shared__ unsigned short Bs[128 * 32];
  const int tid = threadIdx.x;
  const int w = tid >> 6, lane = tid & 63;
  const int bm = blockIdx.y * 128, bn = blockIdx.x * 128;
  const int wr = w >> 1, wc = w & 1;
  const int row0 = w * 16 + (lane >> 2);
  const int s_slot = lane & 3;

  int aoff[4], boff[4];
  const int cchunk = lane >> 4;
#pragma unroll
  for (int i = 0; i < 4; ++i) {
    int ra = wr * 64 + i * 16 + (lane & 15);
    aoff[i] = ra * 64 + ((cchunk ^ ((ra >> 1) & 3)) * 16);
    int rb = wc * 64 + i * 16 + (lane & 15);
    boff[i] = rb * 64 + ((cchunk ^ ((rb >> 1) & 3)) * 16);
  }

  f32x4 acc[4][4];
#pragma unroll
  for (int i = 0; i < 4; ++i)
#pragma unroll
    for (int j = 0; j < 4; ++j) acc[i][j] = (f32x4){0.f, 0.f, 0.f, 0.f};

  for (int k0 = 0; k0 < K; k0 += 32) {
#pragma unroll
    for (int u = 0; u < 2; ++u) {
      int row = row0 + u * 64;
      int c = s_slot ^ ((row >> 1) & 3);
      async16(A + (size_t)(bm + row) * lda + k0 + c * 8, (char*)As + u * 4096 + w * 1024);
      async16(B + (size_t)(bn + row) * ldb + k0 + c * 8, (char*)Bs + u * 4096 + w * 1024);
    }
    __syncthreads();
    bf16x8 af[4], bf[4];
#pragma unroll
    for (int i = 0; i < 4; ++i) {
      af[i] = *(const bf16x8*)((const char*)As + aoff[i]);
      bf[i] = *(const bf16x8*)((const char*)Bs + boff[i]);
    }
#pragma unroll
    for (int i = 0; i < 4; ++i)
#pragma unroll
      for (int j = 0; j < 4; ++j)
        acc[i][j] = __builtin_amdgcn_mfma_f32_16x16x32_bf16(af[i], bf[j], acc[i][j], 0, 0, 0);
    __syncthreads();
  }

#pragma unroll
  for (int i = 0; i < 4; ++i) {
#pragma unroll
    for (int j = 0; j < 4; ++j) {
      int ncol = bn + wc * 64 + j * 16 + (lane & 15);
      float bv = 0.f;
      if (HASBIAS) bv = bias[ncol];
#pragma unroll
      for (int r = 0; r < 4; ++r) {
        int mrow = bm + wr * 64 + i * 16 + (lane >> 4) * 4 + r;
        float v = acc[i][j][r] + bv;
        if (ACT == 1) v = silu_f(v);
        if (ACT == 2) v = softplus_f(v);
        Cbf[(size_t)mrow * ldc + ncol] = f2b(v);
      }
    }
  }
}

// ---------------------------------------------------------------------------
// Merged batched NT MFMA GEMM: 2 problems x 16 batches in one dispatch.
// prob 0: Yt[b][p][c] = W_out[p,:] . yg[b][c,:]          (no bias/act)
// prob 1: Rt[b][p][c] = silu(W_sp[p,:] . x[b][c,:]+b[p]) (bias per-M + silu)
// M=1024, N=512, K=1024; lda=ldb=1024, ldc=512. grid (4, 8, 32).
// ---------------------------------------------------------------------------
__global__ __launch_bounds__(256) void gemm_bat2(
    const unsigned short* __restrict__ A0, const unsigned short* __restrict__ A1,
    const unsigned short* __restrict__ B0, const unsigned short* __restrict__ B1,
    const float* __restrict__ bias1,
    unsigned short* __restrict__ C0, unsigned short* __restrict__ C1) {
  __shared__ unsigned short As[128 * 32];
  __shared__ unsigned short Bs[128 * 32];
  const int zz = blockIdx.z;
  const int prob = zz >> 4, b = zz & 15;
  const unsigned short* A = prob ? A1 : A0;
  const unsigned short* B = (prob ? B1 : B0) + (size_t)b * 524288;
  unsigned short* C = (prob ? C1 : C0) + (size_t)b * 524288;
  const int tid = threadIdx.x;
  const int w = tid >> 6, lane = tid & 63;
  const int bm = blockIdx.y * 128, bn = blockIdx.x * 128;
  const int wr = w >> 1, wc = w & 1;
  const int row0 = w * 16 + (lane >> 2);
  const int s_slot = lane & 3;

  int aoff[4], boff[4];
  const int cchunk = lane >> 4;
#pragma unroll
  for (int i = 0; i < 4; ++i) {
    int ra = wr * 64 + i * 16 + (lane & 15);
    aoff[i] = ra * 64 + ((cchunk ^ ((ra >> 1) & 3)) * 16);
    int rb = wc * 64 + i * 16 + (lane & 15);
    boff[i] = rb * 64 + ((cchunk ^ ((rb >> 1) & 3)) * 16);
  }

  f32x4 acc[4][4];
#pragma unroll
  for (int i = 0; i < 4; ++i)
#pragma unroll
    for (int j = 0; j < 4; ++j) acc[i][j] = (f32x4){0.f, 0.f, 0.f, 0.f};

  for (int k0 = 0; k0 < 1024; k0 += 32) {
#pragma unroll
    for (int u = 0; u < 2; ++u) {
      int row = row0 + u * 64;
      int c = s_slot ^ ((row >> 1) & 3);
      async16(A + (size_t)(bm + row) * 1024 + k0 + c * 8, (char*)As + u * 4096 + w * 1024);
      async16(B + (size_t)(bn + row) * 1024 + k0 + c * 8, (char*)Bs + u * 4096 + w * 1024);
    }
    __syncthreads();
    bf16x8 af[4], bf[4];
#pragma unroll
    for (int i = 0; i < 4; ++i) {
      af[i] = *(const bf16x8*)((const char*)As + aoff[i]);
      bf[i] = *(const bf16x8*)((const char*)Bs + boff[i]);
    }
#pragma unroll
    for (int i = 0; i < 4; ++i)
#pragma unroll
      for (int j = 0; j < 4; ++j)
        acc[i][j] = __builtin_amdgcn_mfma_f32_16x16x32_bf16(af[i], bf[j], acc[i][j], 0, 0, 0);
    __syncthreads();
  }

#pragma unroll
  for (int i = 0; i < 4; ++i) {
#pragma unroll
    for (int j = 0; j < 4; ++j) {
      int ncol = bn + wc * 64 + j * 16 + (lane & 15);
#pragma unroll
      for (int r = 0; r < 4; ++r) {
        int mrow = bm + wr * 64 + i * 16 + (lane >> 4) * 4 + r;
        float v = acc[i][j][r];
        if (prob) v = silu_f(v + bias1[mrow]);
        C[(size_t)mrow * 512 + ncol] = f2b(v);
      }
    }
  }
}

// ---------------------------------------------------------------------------
// Final dual bf16 MFMA GEMM (batched, fp32 out), single-buffered.
// ---------------------------------------------------------------------------
__global__ __launch_bounds__(256) void gemm_dual_mfma(
    const unsigned short* __restrict__ W1, const unsigned short* __restrict__ W2,
    const float* __restrict__ b1, const float* __restrict__ b2,
    const unsigned short* __restrict__ Yt, const unsigned short* __restrict__ Rt,
    float* __restrict__ out) {
  __shared__ unsigned short As1[128 * 32], As2[128 * 32];
  __shared__ unsigned short Bs1[128 * 32], Bs2[128 * 32];
  const int b = blockIdx.z;
  const unsigned short* Ytb = Yt + (size_t)b * 524288;
  const unsigned short* Rtb = Rt + (size_t)b * 524288;
  const int tid = threadIdx.x;
  const int w = tid >> 6, lane = tid & 63;
  const int bm = blockIdx.y * 128, bn = blockIdx.x * 128;
  const int wr = w >> 1, wc = w & 1;
  const int row0 = w * 16 + (lane >> 2);
  const int s_slot = lane & 3;

  int aoff[4], boff[4];
  const int cchunk = lane >> 4;
#pragma unroll
  for (int i = 0; i < 4; ++i) {
    int ra = wr * 64 + i * 16 + (lane & 15);
    aoff[i] = ra * 64 + ((cchunk ^ ((ra >> 1) & 3)) * 16);
    int rb = wc * 64 + i * 16 + (lane & 15);
    boff[i] = rb * 64 + ((cchunk ^ ((rb >> 1) & 3)) * 16);
  }

  f32x4 acc1[4][4], acc2[4][4];
#pragma unroll
  for (int i = 0; i < 4; ++i)
#pragma unroll
    for (int j = 0; j < 4; ++j) {
      acc1[i][j] = (f32x4){0.f, 0.f, 0.f, 0.f};
      acc2[i][j] = (f32x4){0.f, 0.f, 0.f, 0.f};
    }

  for (int k0 = 0; k0 < 512; k0 += 32) {
#pragma unroll
    for (int u = 0; u < 2; ++u) {
      int row = row0 + u * 64;
      int c = s_slot ^ ((row >> 1) & 3);
      async16(W1 + (size_t)(bm + row) * 512 + k0 + c * 8, (char*)As1 + u * 4096 + w * 1024);
      async16(W2 + (size_t)(bm + row) * 512 + k0 + c * 8, (char*)As2 + u * 4096 + w * 1024);
      async16(Ytb + (size_t)(bn + row) * 512 + k0 + c * 8, (char*)Bs1 + u * 4096 + w * 1024);
      async16(Rtb + (size_t)(bn + row) * 512 + k0 + c * 8, (char*)Bs2 + u * 4096 + w * 1024);
    }
    __syncthreads();
    {
      bf16x8 af[4], bf[4];
#pragma unroll
      for (int i = 0; i < 4; ++i) {
        af[i] = *(const bf16x8*)((const char*)As1 + aoff[i]);
        bf[i] = *(const bf16x8*)((const char*)Bs1 + boff[i]);
      }
#pragma unroll
      for (int i = 0; i < 4; ++i)
#pragma unroll
        for (int j = 0; j < 4; ++j)
          acc1[i][j] = __builtin_amdgcn_mfma_f32_16x16x32_bf16(af[i], bf[j], acc1[i][j], 0, 0, 0);
    }
    {
      bf16x8 af[4], bf[4];
#pragma unroll
      for (int i = 0; i < 4; ++i) {
        af[i] = *(const bf16x8*)((const char*)As2 + aoff[i]);
        bf[i] = *(const bf16x8*)((const char*)Bs2 + boff[i]);
      }
#pragma unroll
      for (int i = 0; i < 4; ++i)
#pragma unroll
        for (int j = 0; j < 4; ++j)
          acc2[i][j] = __builtin_amdgcn_mfma_f32_16x16x32_bf16(af[i], bf[j], acc2[i][j], 0, 0, 0);
    }
    __syncthreads();
  }

  float* outb = out + (size_t)b * 524288;
#pragma unroll
  for (int i = 0; i < 4; ++i) {
#pragma unroll
    for (int j = 0; j < 4; ++j) {
      int ncol = bn + wc * 64 + j * 16 + (lane & 15);
#pragma unroll
      for (int r = 0; r < 4; ++r) {
        int mrow = bm + wr * 64 + i * 16 + (lane >> 4) * 4 + r;
        float v = silu_f(acc1[i][j][r] + b1[mrow]) + silu_f(acc2[i][j][r] + b2[mrow]);
        outb[(size_t)mrow * 1024 + ncol] = v;
      }
    }
  }
}

// ---------------------------------------------------------------------------
// Fused segmented cast: all fp32->bf16 weight/input casts in ONE launch.
// Segment boundaries in float4 units.
// ---------------------------------------------------------------------------
__global__ __launch_bounds__(256) void fused_cast(
    const float* __restrict__ x, const float* __restrict__ w_in,
    const float* __restrict__ w_out, const float* __restrict__ w_linsp,
    const float* __restrict__ w_dt, const float* __restrict__ w_lin3,
    const float* __restrict__ w_linres,
    unsigned short* __restrict__ o_x, unsigned short* __restrict__ o_in,
    unsigned short* __restrict__ o_out, unsigned short* __restrict__ o_linsp,
    unsigned short* __restrict__ o_dt, unsigned short* __restrict__ o_lin3,
    unsigned short* __restrict__ o_linres) {
  int v = blockIdx.x * 256 + threadIdx.x;
  const float* src;
  unsigned short* dst;
  int base;
  if (v < 2097152)      { src = x;        dst = o_x;      base = 0; }
  else if (v < 2621440) { src = w_in;     dst = o_in;     base = 2097152; }
  else if (v < 2883584) { src = w_out;    dst = o_out;    base = 2621440; }
  else if (v < 3145728) { src = w_linsp;  dst = o_linsp;  base = 2883584; }
  else if (v < 3162112) { src = w_dt;     dst = o_dt;     base = 3145728; }
  else if (v < 3227648) { src = w_lin3;   dst = o_lin3;   base = 3162112; }
  else                  { src = w_linres; dst = o_linres; base = 3227648; }
  int i = (v - base) * 4;
  float4 val = *(const float4*)(src + i);
  ushort4 o;
  o.x = f2b(val.x); o.y = f2b(val.y); o.z = f2b(val.z); o.w = f2b(val.w);
  *(ushort4*)(dst + i) = o;
}

// Transpose-cast x_proj_w rows 0..63 -> xpT[k*64+r] = xp[r*1024+k], bf16.
__global__ __launch_bounds__(256) void transpose_cast_xp(const float* __restrict__ in,
                                                         unsigned short* __restrict__ out) {
  int idx = blockIdx.x * 256 + threadIdx.x;  // 65536 total
  int k = idx >> 6;
  int r = idx & 63;
  out[idx] = f2b(in[r * 1024 + k]);
}

// ---------------------------------------------------------------------------
// BC[m][j] = sum_k xs[m][k] * x_proj_w[64+j][k], j=0..3 (fp32 weights, L2-hot).
// ---------------------------------------------------------------------------
__global__ __launch_bounds__(256) void bc_kernel(
    const unsigned short* __restrict__ xs, const float* __restrict__ xp_w,
    float* __restrict__ BC) {
  const int wave = threadIdx.x >> 6, lane = threadIdx.x & 63;
  const int m = blockIdx.x * 4 + wave;
  const unsigned short* row = xs + (size_t)m * 1024;
  const float* w0 = xp_w + 64 * 1024;
  float s0 = 0.f, s1 = 0.f, s2 = 0.f, s3 = 0.f;
#pragma unroll
  for (int e = 0; e < 16; ++e) {
    int k = lane + e * 64;
    float xv = b2f(row[k]);
    s0 = fmaf(xv, w0[k], s0);
    s1 = fmaf(xv, w0[1024 + k], s1);
    s2 = fmaf(xv, w0[2048 + k], s2);
    s3 = fmaf(xv, w0[3072 + k], s3);
  }
#pragma unroll
  for (int off = 32; off > 0; off >>= 1) {
    s0 += __shfl_down(s0, off);
    s1 += __shfl_down(s1, off);
    s2 += __shfl_down(s2, off);
    s3 += __shfl_down(s3, off);
  }
  if (lane == 0) *(float4*)(BC + (size_t)m * 4) = make_float4(s0, s1, s2, s3);
}

// ---------------------------------------------------------------------------
// Causal depthwise conv4 + bias + SiLU, bf16 in/out; input row-stride instride.
// ---------------------------------------------------------------------------
__global__ __launch_bounds__(256) void conv_silu_bf16(
    const unsigned short* __restrict__ xin, int instride, const float* __restrict__ w,
    const float* __restrict__ cb, unsigned short* __restrict__ xout) {
  int idx = blockIdx.x * 256 + threadIdx.x;
  int d = idx & 1023;
  int l = (idx >> 10) & 511;
  int b = idx >> 19;
  const unsigned short* base = xin + ((size_t)b * 512) * instride + d;
  float acc = cb[d];
  float4 wv = *(const float4*)(w + d * 4);
  float wj[4] = {wv.x, wv.y, wv.z, wv.w};
#pragma unroll
  for (int j = 0; j < 4; ++j) {
    int ll = l - 3 + j;
    if (ll >= 0) acc = fmaf(wj[j], b2f(base[(size_t)ll * instride]), acc);
  }
  xout[idx] = f2b(silu_f(acc));
}

// ---------------------------------------------------------------------------
// Chunked selective scan; delta/z read with row-stride dzstride (xz layout).
// ---------------------------------------------------------------------------
__global__ __launch_bounds__(1024) void scan_chunked(
    const unsigned short* __restrict__ delta, const unsigned short* __restrict__ z,
    int dzstride,
    const unsigned short* __restrict__ xs, const float* __restrict__ BC,
    const float* __restrict__ A_log, const float* __restrict__ D_ssm,
    unsigned short* __restrict__ yout) {
  __shared__ float4 ps[16][64];
  const int d_l = threadIdx.x & 63;
  const int ck = threadIdx.x >> 6;
  const int b = blockIdx.y;
  const int d = blockIdx.x * 64 + d_l;
  const float A0 = -expf(A_log[d * 2 + 0]);
  const float A1 = -expf(A_log[d * 2 + 1]);
  const size_t dzbase = ((size_t)b * 512 + ck * 32) * dzstride + d;
  const size_t base = ((size_t)b * 512 + ck * 32) * 1024 + d;
  const size_t bcb = ((size_t)b * 512 + ck * 32) * 4;

  float h0 = 0.f, h1 = 0.f, sumdl = 0.f;
  for (int i = 0; i < 32; ++i) {
    float dl = b2f(delta[dzbase + (size_t)i * dzstride]);
    float xv = b2f(xs[base + (size_t)i * 1024]);
    const float* q = BC + bcb + i * 4;
    sumdl += dl;
    float dx = dl * xv;
    h0 = fmaf(expf(dl * A0), h0, dx * q[0]);
    h1 = fmaf(expf(dl * A1), h1, dx * q[1]);
  }
  ps[ck][d_l] = make_float4(expf(A0 * sumdl), expf(A1 * sumdl), h0, h1);
  __syncthreads();

  h0 = 0.f; h1 = 0.f;
  for (int k = 0; k < ck; ++k) {
    float4 s = ps[k][d_l];
    h0 = fmaf(s.x, h0, s.z);
    h1 = fmaf(s.y, h1, s.w);
  }

  const float Dd = D_ssm[d];
  for (int i = 0; i < 32; ++i) {
    float dl = b2f(delta[dzbase + (size_t)i * dzstride]);
    size_t off = base + (size_t)i * 1024;
    float xv = b2f(xs[off]);
    const float* q = BC + bcb + i * 4;
    float dx = dl * xv;
    h0 = fmaf(expf(dl * A0), h0, dx * q[0]);
    h1 = fmaf(expf(dl * A1), h1, dx * q[1]);
    float y = fmaf(xv, Dd, fmaf(h0, q[2], h1 * q[3]));
    y *= silu_f(b2f(z[dzbase + (size_t)i * dzstride]));
    yout[off] = f2b(y);
  }
}

// ---------------------------------------------------------------------------
// Column LayerNorm on Yt[b][p][c]: stats over p per (b,c); g/bias indexed by p.
// ---------------------------------------------------------------------------
__global__ __launch_bounds__(256) void ln_col(unsigned short* __restrict__ Yt,
                                              const float* __restrict__ g,
                                              const float* __restrict__ be) {
  __shared__ float ps[4][64], ps2[4][64];
  const int b = blockIdx.y, cc = blockIdx.x * 64;
  const int cl = threadIdx.x & 63, pg = threadIdx.x >> 6;
  unsigned short* base = Yt + (size_t)b * 524288 + cc + cl;
  float s = 0.f, s2 = 0.f;
  const int p0 = pg * 256;
  for (int p = p0; p < p0 + 256; ++p) {
    float v = b2f(base[(size_t)p * 512]);
    s += v; s2 += v * v;
  }
  ps[pg][cl] = s; ps2[pg][cl] = s2;
  __syncthreads();
  float S = ps[0][cl] + ps[1][cl] + ps[2][cl] + ps[3][cl];
  float S2 = ps2[0][cl] + ps2[1][cl] + ps2[2][cl] + ps2[3][cl];
  float mu = S * (1.f / 1024.f);
  float var = S2 * (1.f / 1024.f) - mu * mu;
  float rstd = rsqrtf(var + 1e-5f);
  for (int p = p0; p < p0 + 256; ++p) {
    float v = b2f(base[(size_t)p * 512]);
    base[(size_t)p * 512] = f2b((v - mu) * rstd * g[p] + be[p]);
  }
}

// ---------------------------------------------------------------------------
extern "C" void kernel_launch(void* const* d_in, const int* in_sizes, int n_in,
                              void* d_out, int out_size, void* d_ws, size_t ws_size,
                              hipStream_t stream) {
  const float* x          = (const float*)d_in[0];
  const float* in_proj_w  = (const float*)d_in[1];
  const float* conv_w     = (const float*)d_in[2];
  const float* conv_b     = (const float*)d_in[3];
  const float* x_proj_w   = (const float*)d_in[4];
  const float* dt_proj_w  = (const float*)d_in[5];
  const float* dt_proj_b  = (const float*)d_in[6];
  const float* A_log      = (const float*)d_in[7];
  const float* D_ssm      = (const float*)d_in[8];
  const float* out_proj_w = (const float*)d_in[9];
  const float* ln_g       = (const float*)d_in[10];
  const float* ln_b       = (const float*)d_in[11];
  const float* lin3_w     = (const float*)d_in[12];
  const float* lin3_b     = (const float*)d_in[13];
  const float* linsp_w    = (const float*)d_in[14];
  const float* linsp_b    = (const float*)d_in[15];
  const float* linres_w   = (const float*)d_in[16];
  const float* linres_b   = (const float*)d_in[17];
  float* out = (float*)d_out;

  char* ws = (char*)d_ws;
  const size_t MB = 1024 * 1024;
  unsigned short* w_in_bf     = (unsigned short*)(ws + 0);                     // 4 MB
  unsigned short* w_out_bf    = (unsigned short*)(ws + 4 * MB);                // 2 MB
  unsigned short* w_linsp_bf  = (unsigned short*)(ws + 6 * MB);                // 2 MB
  unsigned short* w_dt_bf     = (unsigned short*)(ws + 8 * MB);                // 128 KB
  unsigned short* xpT_bf      = (unsigned short*)(ws + 8 * MB + 128 * 1024);   // 128 KB
  float*          BC          = (float*)(ws + 8 * MB + 256 * 1024);            // 128 KB
  unsigned short* W_eff       = (unsigned short*)(ws + 9 * MB);                // 2 MB
  unsigned short* w_lin3_bf   = (unsigned short*)(ws + 11 * MB);               // 512 KB
  unsigned short* w_linres_bf = (unsigned short*)(ws + 11 * MB + 512 * 1024);  // 512 KB
  unsigned short* x_bf  = (unsigned short*)(ws + 16 * MB);  // 16 MB
  unsigned short* xz    = (unsigned short*)(ws + 32 * MB);  // 32 MB: [8192][2048] xs_pre|z -> delta|z -> Rt
  unsigned short* seg3  = (unsigned short*)(ws + 64 * MB);  // 16 MB: xs -> Yt
  unsigned short* seg4  = (unsigned short*)(ws + 80 * MB);  // 16 MB: y_gated

  dim3 blk(256);
  // 1: all casts fused (x + 6 weights)
  fused_cast<<<12864, blk, 0, stream>>>(x, in_proj_w, out_proj_w, linsp_w,
                                        dt_proj_w, lin3_w, linres_w,
                                        x_bf, w_in_bf, w_out_bf, w_linsp_bf,
                                        w_dt_bf, w_lin3_bf, w_linres_bf);
  // 2: transpose-cast x_proj rows 0..63
  transpose_cast_xp<<<256, blk, 0, stream>>>(x_proj_w, xpT_bf);
  // 3: W_eff = dt_proj_w @ x_proj_w[0:64]  (M=1024, N=1024, K=64)
  gemm_bf16_nt<0, 0><<<dim3(8, 8), blk, 0, stream>>>(
      w_dt_bf, 64, xpT_bf, 64, nullptr, W_eff, 1024, 64);
  // 4: in_proj merged (N=2048) -> xz
  gemm_bf16_nt<0, 0><<<dim3(16, 64), blk, 0, stream>>>(
      x_bf, 1024, w_in_bf, 1024, nullptr, xz, 2048, 1024);
  // 5: conv + silu -> xs (seg3); reads xz cols 0-1023
  conv_silu_bf16<<<32768, blk, 0, stream>>>(xz, 2048, conv_w, conv_b, seg3);
  // 6: BC = xs . x_proj_w[64:68]^T  (fp32)
  bc_kernel<<<2048, blk, 0, stream>>>(seg3, x_proj_w, BC);
  // 7: delta = softplus(xs . W_eff^T + dt_proj_b) -> xz cols 0-1023
  gemm_bf16_nt<2, 1><<<dim3(8, 64), blk, 0, stream>>>(
      seg3, 1024, W_eff, 1024, dt_proj_b, xz, 2048, 1024);
  // 8: chunked scan -> y_gated (seg4)
  scan_chunked<<<dim3(16, 16), dim3(1024), 0, stream>>>(
      xz, xz + 1024, 2048, seg3, BC, A_log, D_ssm, seg4);
  // 9: merged batched GEMM: Yt -> seg3 (xs dead), Rt -> xz (delta/z dead)
  gemm_bat2<<<dim3(4, 8, 32), blk, 0, stream>>>(
      w_out_bf, w_linsp_bf, seg4, x_bf, linsp_b, seg3, xz);
  // 10: column LayerNorm on Yt
  ln_col<<<dim3(8, 16), blk, 0, stream>>>(seg3, ln_g, ln_b);
  // 11: fused final dual MFMA
  gemm_dual_mfma<<<dim3(8, 4, 16), blk, 0, stream>>>(
      w_lin3_bf, w_linres_bf, lin3_b, linres_b, seg3, xz, out);
}

// Round 11
// 431.483 us; speedup vs baseline: 1.4722x; 1.0932x over previous
//
#include <hip/hip_runtime.h>
#include <math.h>

typedef __attribute__((ext_vector_type(8))) short bf16x8;
typedef __attribute__((ext_vector_type(4))) float f32x4;

#define DEV_INLINE __device__ __forceinline__

DEV_INLINE float silu_f(float v) { return v / (1.f + expf(-v)); }
DEV_INLINE float softplus_f(float v) { return (v > 20.f) ? v : log1pf(expf(v)); }
DEV_INLINE float b2f(unsigned short u) { return __uint_as_float(((unsigned int)u) << 16); }
DEV_INLINE unsigned short f2b(float f) {
  unsigned int u = __float_as_uint(f);
  return (unsigned short)((u + 0x7FFFu + ((u >> 16) & 1u)) >> 16);
}
DEV_INLINE void async16(const void* g, void* l) {
  __builtin_amdgcn_global_load_lds((const __attribute__((address_space(1))) unsigned int*)g,
                                   (__attribute__((address_space(3))) unsigned int*)l, 16, 0, 0);
}

// ---------------------------------------------------------------------------
// bf16 NT MFMA GEMM, BK=64 (single-buffered 2-barrier structure — r6 showed
// hand-pipelining regresses; BK=64 instead halves the per-iter barrier drains).
// C[m,n] = act( sum_k A[m*lda+k]*B[n*ldb+k] + bias[n] ), K multiple of 64.
// BM=BN=128, 256 thr (4 waves 2x2), wave tile 64x64.
// LDS tile [128][64] bf16 (128B rows); staged slot s holds global 16B-chunk
// c = s ^ (row&7)  (lane-linear dest, per-lane source — both-sides swizzle).
// Fragment read chunk = (ks*4 + (lane>>4)) ^ (lane&7)  -> 2 lanes/bank (free).
// ---------------------------------------------------------------------------
template <int ACT, int HASBIAS>
__global__ __launch_bounds__(256) void gemm_bf16_nt64(
    const unsigned short* __restrict__ A, int lda,
    const unsigned short* __restrict__ B, int ldb,
    const float* __restrict__ bias,
    unsigned short* __restrict__ Cbf, int ldc, int K) {
  __shared__ unsigned short As[128 * 64];
  __shared__ unsigned short Bs[128 * 64];
  const int tid = threadIdx.x;
  const int w = tid >> 6, lane = tid & 63;
  const int bm = blockIdx.y * 128, bn = blockIdx.x * 128;
  const int wr = w >> 1, wc = w & 1;

  // staging: row = u*32 + w*8 + (lane>>3), slot = lane&7, chunk = slot^(lane>>3)
  const int srow = w * 8 + (lane >> 3);
  const int schunk = (lane & 7) ^ (lane >> 3);

  // fragment offsets
  int aoff[4][2], boff[4][2];
  const int l15 = lane & 15, g = lane >> 4, xr = lane & 7;
#pragma unroll
  for (int i = 0; i < 4; ++i) {
    int ra = wr * 64 + i * 16 + l15;
    int rb = wc * 64 + i * 16 + l15;
#pragma unroll
    for (int ks = 0; ks < 2; ++ks) {
      int ch = (ks * 4 + g) ^ xr;
      aoff[i][ks] = ra * 128 + ch * 16;
      boff[i][ks] = rb * 128 + ch * 16;
    }
  }

  f32x4 acc[4][4];
#pragma unroll
  for (int i = 0; i < 4; ++i)
#pragma unroll
    for (int j = 0; j < 4; ++j) acc[i][j] = (f32x4){0.f, 0.f, 0.f, 0.f};

  for (int k0 = 0; k0 < K; k0 += 64) {
#pragma unroll
    for (int u = 0; u < 4; ++u) {
      int row = u * 32 + srow;
      async16(A + (size_t)(bm + row) * lda + k0 + schunk * 8, (char*)As + u * 4096 + w * 1024);
      async16(B + (size_t)(bn + row) * ldb + k0 + schunk * 8, (char*)Bs + u * 4096 + w * 1024);
    }
    __syncthreads();
#pragma unroll
    for (int ks = 0; ks < 2; ++ks) {
      bf16x8 af[4], bf[4];
#pragma unroll
      for (int i = 0; i < 4; ++i) {
        af[i] = *(const bf16x8*)((const char*)As + aoff[i][ks]);
        bf[i] = *(const bf16x8*)((const char*)Bs + boff[i][ks]);
      }
#pragma unroll
      for (int i = 0; i < 4; ++i)
#pragma unroll
        for (int j = 0; j < 4; ++j)
          acc[i][j] = __builtin_amdgcn_mfma_f32_16x16x32_bf16(af[i], bf[j], acc[i][j], 0, 0, 0);
    }
    __syncthreads();
  }

#pragma unroll
  for (int i = 0; i < 4; ++i) {
#pragma unroll
    for (int j = 0; j < 4; ++j) {
      int ncol = bn + wc * 64 + j * 16 + (lane & 15);
      float bv = 0.f;
      if (HASBIAS) bv = bias[ncol];
#pragma unroll
      for (int r = 0; r < 4; ++r) {
        int mrow = bm + wr * 64 + i * 16 + (lane >> 4) * 4 + r;
        float v = acc[i][j][r] + bv;
        if (ACT == 1) v = silu_f(v);
        if (ACT == 2) v = softplus_f(v);
        Cbf[(size_t)mrow * ldc + ncol] = f2b(v);
      }
    }
  }
}

// ---------------------------------------------------------------------------
// Merged batched NT MFMA GEMM (BK=64): 2 problems x 16 batches, one dispatch.
// prob 0: Yt[b][p][c] = W_out[p,:] . yg[b][c,:]
// prob 1: Rt[b][p][c] = silu(W_sp[p,:] . x[b][c,:] + b[p])
// M=1024, N=512, K=1024; lda=ldb=1024, ldc=512. grid (4, 8, 32).
// ---------------------------------------------------------------------------
__global__ __launch_bounds__(256) void gemm_bat2_64(
    const unsigned short* __restrict__ A0, const unsigned short* __restrict__ A1,
    const unsigned short* __restrict__ B0, const unsigned short* __restrict__ B1,
    const float* __restrict__ bias1,
    unsigned short* __restrict__ C0, unsigned short* __restrict__ C1) {
  __shared__ unsigned short As[128 * 64];
  __shared__ unsigned short Bs[128 * 64];
  const int zz = blockIdx.z;
  const int prob = zz >> 4, b = zz & 15;
  const unsigned short* A = prob ? A1 : A0;
  const unsigned short* B = (prob ? B1 : B0) + (size_t)b * 524288;
  unsigned short* C = (prob ? C1 : C0) + (size_t)b * 524288;
  const int tid = threadIdx.x;
  const int w = tid >> 6, lane = tid & 63;
  const int bm = blockIdx.y * 128, bn = blockIdx.x * 128;
  const int wr = w >> 1, wc = w & 1;

  const int srow = w * 8 + (lane >> 3);
  const int schunk = (lane & 7) ^ (lane >> 3);

  int aoff[4][2], boff[4][2];
  const int l15 = lane & 15, g = lane >> 4, xr = lane & 7;
#pragma unroll
  for (int i = 0; i < 4; ++i) {
    int ra = wr * 64 + i * 16 + l15;
    int rb = wc * 64 + i * 16 + l15;
#pragma unroll
    for (int ks = 0; ks < 2; ++ks) {
      int ch = (ks * 4 + g) ^ xr;
      aoff[i][ks] = ra * 128 + ch * 16;
      boff[i][ks] = rb * 128 + ch * 16;
    }
  }

  f32x4 acc[4][4];
#pragma unroll
  for (int i = 0; i < 4; ++i)
#pragma unroll
    for (int j = 0; j < 4; ++j) acc[i][j] = (f32x4){0.f, 0.f, 0.f, 0.f};

  for (int k0 = 0; k0 < 1024; k0 += 64) {
#pragma unroll
    for (int u = 0; u < 4; ++u) {
      int row = u * 32 + srow;
      async16(A + (size_t)(bm + row) * 1024 + k0 + schunk * 8, (char*)As + u * 4096 + w * 1024);
      async16(B + (size_t)(bn + row) * 1024 + k0 + schunk * 8, (char*)Bs + u * 4096 + w * 1024);
    }
    __syncthreads();
#pragma unroll
    for (int ks = 0; ks < 2; ++ks) {
      bf16x8 af[4], bf[4];
#pragma unroll
      for (int i = 0; i < 4; ++i) {
        af[i] = *(const bf16x8*)((const char*)As + aoff[i][ks]);
        bf[i] = *(const bf16x8*)((const char*)Bs + boff[i][ks]);
      }
#pragma unroll
      for (int i = 0; i < 4; ++i)
#pragma unroll
        for (int j = 0; j < 4; ++j)
          acc[i][j] = __builtin_amdgcn_mfma_f32_16x16x32_bf16(af[i], bf[j], acc[i][j], 0, 0, 0);
    }
    __syncthreads();
  }

#pragma unroll
  for (int i = 0; i < 4; ++i) {
#pragma unroll
    for (int j = 0; j < 4; ++j) {
      int ncol = bn + wc * 64 + j * 16 + (lane & 15);
#pragma unroll
      for (int r = 0; r < 4; ++r) {
        int mrow = bm + wr * 64 + i * 16 + (lane >> 4) * 4 + r;
        float v = acc[i][j][r];
        if (prob) v = silu_f(v + bias1[mrow]);
        C[(size_t)mrow * 512 + ncol] = f2b(v);
      }
    }
  }
}

// ---------------------------------------------------------------------------
// Final dual bf16 MFMA GEMM (batched, fp32 out), BK=32 (4 operand buffers).
// ---------------------------------------------------------------------------
__global__ __launch_bounds__(256) void gemm_dual_mfma(
    const unsigned short* __restrict__ W1, const unsigned short* __restrict__ W2,
    const float* __restrict__ b1, const float* __restrict__ b2,
    const unsigned short* __restrict__ Yt, const unsigned short* __restrict__ Rt,
    float* __restrict__ out) {
  __shared__ unsigned short As1[128 * 32], As2[128 * 32];
  __shared__ unsigned short Bs1[128 * 32], Bs2[128 * 32];
  const int b = blockIdx.z;
  const unsigned short* Ytb = Yt + (size_t)b * 524288;
  const unsigned short* Rtb = Rt + (size_t)b * 524288;
  const int tid = threadIdx.x;
  const int w = tid >> 6, lane = tid & 63;
  const int bm = blockIdx.y * 128, bn = blockIdx.x * 128;
  const int wr = w >> 1, wc = w & 1;
  const int row0 = w * 16 + (lane >> 2);
  const int s_slot = lane & 3;

  int aoff[4], boff[4];
  const int cchunk = lane >> 4;
#pragma unroll
  for (int i = 0; i < 4; ++i) {
    int ra = wr * 64 + i * 16 + (lane & 15);
    aoff[i] = ra * 64 + ((cchunk ^ ((ra >> 1) & 3)) * 16);
    int rb = wc * 64 + i * 16 + (lane & 15);
    boff[i] = rb * 64 + ((cchunk ^ ((rb >> 1) & 3)) * 16);
  }

  f32x4 acc1[4][4], acc2[4][4];
#pragma unroll
  for (int i = 0; i < 4; ++i)
#pragma unroll
    for (int j = 0; j < 4; ++j) {
      acc1[i][j] = (f32x4){0.f, 0.f, 0.f, 0.f};
      acc2[i][j] = (f32x4){0.f, 0.f, 0.f, 0.f};
    }

  for (int k0 = 0; k0 < 512; k0 += 32) {
#pragma unroll
    for (int u = 0; u < 2; ++u) {
      int row = row0 + u * 64;
      int c = s_slot ^ ((row >> 1) & 3);
      async16(W1 + (size_t)(bm + row) * 512 + k0 + c * 8, (char*)As1 + u * 4096 + w * 1024);
      async16(W2 + (size_t)(bm + row) * 512 + k0 + c * 8, (char*)As2 + u * 4096 + w * 1024);
      async16(Ytb + (size_t)(bn + row) * 512 + k0 + c * 8, (char*)Bs1 + u * 4096 + w * 1024);
      async16(Rtb + (size_t)(bn + row) * 512 + k0 + c * 8, (char*)Bs2 + u * 4096 + w * 1024);
    }
    __syncthreads();
    {
      bf16x8 af[4], bf[4];
#pragma unroll
      for (int i = 0; i < 4; ++i) {
        af[i] = *(const bf16x8*)((const char*)As1 + aoff[i]);
        bf[i] = *(const bf16x8*)((const char*)Bs1 + boff[i]);
      }
#pragma unroll
      for (int i = 0; i < 4; ++i)
#pragma unroll
        for (int j = 0; j < 4; ++j)
          acc1[i][j] = __builtin_amdgcn_mfma_f32_16x16x32_bf16(af[i], bf[j], acc1[i][j], 0, 0, 0);
    }
    {
      bf16x8 af[4], bf[4];
#pragma unroll
      for (int i = 0; i < 4; ++i) {
        af[i] = *(const bf16x8*)((const char*)As2 + aoff[i]);
        bf[i] = *(const bf16x8*)((const char*)Bs2 + boff[i]);
      }
#pragma unroll
      for (int i = 0; i < 4; ++i)
#pragma unroll
        for (int j = 0; j < 4; ++j)
          acc2[i][j] = __builtin_amdgcn_mfma_f32_16x16x32_bf16(af[i], bf[j], acc2[i][j], 0, 0, 0);
    }
    __syncthreads();
  }

  float* outb = out + (size_t)b * 524288;
#pragma unroll
  for (int i = 0; i < 4; ++i) {
#pragma unroll
    for (int j = 0; j < 4; ++j) {
      int ncol = bn + wc * 64 + j * 16 + (lane & 15);
#pragma unroll
      for (int r = 0; r < 4; ++r) {
        int mrow = bm + wr * 64 + i * 16 + (lane >> 4) * 4 + r;
        float v = silu_f(acc1[i][j][r] + b1[mrow]) + silu_f(acc2[i][j][r] + b2[mrow]);
        outb[(size_t)mrow * 1024 + ncol] = v;
      }
    }
  }
}

// ---------------------------------------------------------------------------
// Fused segmented cast: all fp32->bf16 weight/input casts in ONE launch.
// ---------------------------------------------------------------------------
__global__ __launch_bounds__(256) void fused_cast(
    const float* __restrict__ x, const float* __restrict__ w_in,
    const float* __restrict__ w_out, const float* __restrict__ w_linsp,
    const float* __restrict__ w_dt, const float* __restrict__ w_lin3,
    const float* __restrict__ w_linres,
    unsigned short* __restrict__ o_x, unsigned short* __restrict__ o_in,
    unsigned short* __restrict__ o_out, unsigned short* __restrict__ o_linsp,
    unsigned short* __restrict__ o_dt, unsigned short* __restrict__ o_lin3,
    unsigned short* __restrict__ o_linres) {
  int v = blockIdx.x * 256 + threadIdx.x;
  const float* src;
  unsigned short* dst;
  int base;
  if (v < 2097152)      { src = x;        dst = o_x;      base = 0; }
  else if (v < 2621440) { src = w_in;     dst = o_in;     base = 2097152; }
  else if (v < 2883584) { src = w_out;    dst = o_out;    base = 2621440; }
  else if (v < 3145728) { src = w_linsp;  dst = o_linsp;  base = 2883584; }
  else if (v < 3162112) { src = w_dt;     dst = o_dt;     base = 3145728; }
  else if (v < 3227648) { src = w_lin3;   dst = o_lin3;   base = 3162112; }
  else                  { src = w_linres; dst = o_linres; base = 3227648; }
  int i = (v - base) * 4;
  float4 val = *(const float4*)(src + i);
  ushort4 o;
  o.x = f2b(val.x); o.y = f2b(val.y); o.z = f2b(val.z); o.w = f2b(val.w);
  *(ushort4*)(dst + i) = o;
}

// Transpose-cast x_proj_w rows 0..63 -> xpT[k*64+r] = xp[r*1024+k], bf16.
__global__ __launch_bounds__(256) void transpose_cast_xp(const float* __restrict__ in,
                                                         unsigned short* __restrict__ out) {
  int idx = blockIdx.x * 256 + threadIdx.x;  // 65536 total
  int k = idx >> 6;
  int r = idx & 63;
  out[idx] = f2b(in[r * 1024 + k]);
}

// ---------------------------------------------------------------------------
// Fused conv4 + SiLU + BC reduction. One block per m=(b*512+l), 256 threads,
// 4 d's per thread. xs computed in-register, written bf16; BC[m][0..3]
// block-reduced from the same register values (saves a 16MB re-read pass).
// ---------------------------------------------------------------------------
__global__ __launch_bounds__(256) void conv_bc_fused(
    const unsigned short* __restrict__ xz,  // [8192][2048], cols 0-1023 = xs_pre
    const float* __restrict__ cw, const float* __restrict__ cb,
    const float* __restrict__ xp_w,  // fp32 (68,1024); rows 64..67 used here
    unsigned short* __restrict__ xs_out,  // [8192][1024]
    float* __restrict__ BC) {             // [8192][4]
  __shared__ float red[4][4];  // [wave][j]
  const int m = blockIdx.x;
  const int l = m & 511;
  const int t = threadIdx.x;
  const int d0 = t * 4;
  const int wv = t >> 6, lane = t & 63;

  // conv inputs: rows l-3..l
  float xv[4][4];  // [j][dd]
#pragma unroll
  for (int j = 0; j < 4; ++j) {
    int ll = l - 3 + j;
    if (ll >= 0) {
      ushort4 u = *(const ushort4*)(xz + (size_t)(m - 3 + j) * 2048 + d0);
      xv[j][0] = b2f(u.x); xv[j][1] = b2f(u.y); xv[j][2] = b2f(u.z); xv[j][3] = b2f(u.w);
    } else {
      xv[j][0] = 0.f; xv[j][1] = 0.f; xv[j][2] = 0.f; xv[j][3] = 0.f;
    }
  }
  float xs[4];
  ushort4 o;
#pragma unroll
  for (int dd = 0; dd < 4; ++dd) {
    float4 w4 = *(const float4*)(cw + (d0 + dd) * 4);
    float acc = cb[d0 + dd];
    acc = fmaf(w4.x, xv[0][dd], acc);
    acc = fmaf(w4.y, xv[1][dd], acc);
    acc = fmaf(w4.z, xv[2][dd], acc);
    acc = fmaf(w4.w, xv[3][dd], acc);
    xs[dd] = silu_f(acc);
  }
  o.x = f2b(xs[0]); o.y = f2b(xs[1]); o.z = f2b(xs[2]); o.w = f2b(xs[3]);
  *(ushort4*)(xs_out + (size_t)m * 1024 + d0) = o;

  // BC partials
  float p[4];
#pragma unroll
  for (int j = 0; j < 4; ++j) {
    float4 w4 = *(const float4*)(xp_w + (size_t)(64 + j) * 1024 + d0);
    p[j] = xs[0] * w4.x + xs[1] * w4.y + xs[2] * w4.z + xs[3] * w4.w;
  }
#pragma unroll
  for (int off = 32; off > 0; off >>= 1) {
#pragma unroll
    for (int j = 0; j < 4; ++j) p[j] += __shfl_down(p[j], off);
  }
  if (lane == 0) {
#pragma unroll
    for (int j = 0; j < 4; ++j) red[wv][j] = p[j];
  }
  __syncthreads();
  if (t < 4) BC[(size_t)m * 4 + t] = red[0][t] + red[1][t] + red[2][t] + red[3][t];
}

// ---------------------------------------------------------------------------
// Chunked selective scan; delta/z read with row-stride dzstride (xz layout).
// ---------------------------------------------------------------------------
__global__ __launch_bounds__(1024) void scan_chunked(
    const unsigned short* __restrict__ delta, const unsigned short* __restrict__ z,
    int dzstride,
    const unsigned short* __restrict__ xs, const float* __restrict__ BC,
    const float* __restrict__ A_log, const float* __restrict__ D_ssm,
    unsigned short* __restrict__ yout) {
  __shared__ float4 ps[16][64];
  const int d_l = threadIdx.x & 63;
  const int ck = threadIdx.x >> 6;
  const int b = blockIdx.y;
  const int d = blockIdx.x * 64 + d_l;
  const float A0 = -expf(A_log[d * 2 + 0]);
  const float A1 = -expf(A_log[d * 2 + 1]);
  const size_t dzbase = ((size_t)b * 512 + ck * 32) * dzstride + d;
  const size_t base = ((size_t)b * 512 + ck * 32) * 1024 + d;
  const size_t bcb = ((size_t)b * 512 + ck * 32) * 4;

  float h0 = 0.f, h1 = 0.f, sumdl = 0.f;
  for (int i = 0; i < 32; ++i) {
    float dl = b2f(delta[dzbase + (size_t)i * dzstride]);
    float xv = b2f(xs[base + (size_t)i * 1024]);
    const float* q = BC + bcb + i * 4;
    sumdl += dl;
    float dx = dl * xv;
    h0 = fmaf(expf(dl * A0), h0, dx * q[0]);
    h1 = fmaf(expf(dl * A1), h1, dx * q[1]);
  }
  ps[ck][d_l] = make_float4(expf(A0 * sumdl), expf(A1 * sumdl), h0, h1);
  __syncthreads();

  h0 = 0.f; h1 = 0.f;
  for (int k = 0; k < ck; ++k) {
    float4 s = ps[k][d_l];
    h0 = fmaf(s.x, h0, s.z);
    h1 = fmaf(s.y, h1, s.w);
  }

  const float Dd = D_ssm[d];
  for (int i = 0; i < 32; ++i) {
    float dl = b2f(delta[dzbase + (size_t)i * dzstride]);
    size_t off = base + (size_t)i * 1024;
    float xv = b2f(xs[off]);
    const float* q = BC + bcb + i * 4;
    float dx = dl * xv;
    h0 = fmaf(expf(dl * A0), h0, dx * q[0]);
    h1 = fmaf(expf(dl * A1), h1, dx * q[1]);
    float y = fmaf(xv, Dd, fmaf(h0, q[2], h1 * q[3]));
    y *= silu_f(b2f(z[dzbase + (size_t)i * dzstride]));
    yout[off] = f2b(y);
  }
}

// ---------------------------------------------------------------------------
// Column LayerNorm on Yt[b][p][c]: stats over p per (b,c); g/bias indexed by p.
// ---------------------------------------------------------------------------
__global__ __launch_bounds__(256) void ln_col(unsigned short* __restrict__ Yt,
                                              const float* __restrict__ g,
                                              const float* __restrict__ be) {
  __shared__ float ps[4][64], ps2[4][64];
  const int b = blockIdx.y, cc = blockIdx.x * 64;
  const int cl = threadIdx.x & 63, pg = threadIdx.x >> 6;
  unsigned short* base = Yt + (size_t)b * 524288 + cc + cl;
  float s = 0.f, s2 = 0.f;
  const int p0 = pg * 256;
  for (int p = p0; p < p0 + 256; ++p) {
    float v = b2f(base[(size_t)p * 512]);
    s += v; s2 += v * v;
  }
  ps[pg][cl] = s; ps2[pg][cl] = s2;
  __syncthreads();
  float S = ps[0][cl] + ps[1][cl] + ps[2][cl] + ps[3][cl];
  float S2 = ps2[0][cl] + ps2[1][cl] + ps2[2][cl] + ps2[3][cl];
  float mu = S * (1.f / 1024.f);
  float var = S2 * (1.f / 1024.f) - mu * mu;
  float rstd = rsqrtf(var + 1e-5f);
  for (int p = p0; p < p0 + 256; ++p) {
    float v = b2f(base[(size_t)p * 512]);
    base[(size_t)p * 512] = f2b((v - mu) * rstd * g[p] + be[p]);
  }
}

// ---------------------------------------------------------------------------
extern "C" void kernel_launch(void* const* d_in, const int* in_sizes, int n_in,
                              void* d_out, int out_size, void* d_ws, size_t ws_size,
                              hipStream_t stream) {
  const float* x          = (const float*)d_in[0];
  const float* in_proj_w  = (const float*)d_in[1];
  const float* conv_w     = (const float*)d_in[2];
  const float* conv_b     = (const float*)d_in[3];
  const float* x_proj_w   = (const float*)d_in[4];
  const float* dt_proj_w  = (const float*)d_in[5];
  const float* dt_proj_b  = (const float*)d_in[6];
  const float* A_log      = (const float*)d_in[7];
  const float* D_ssm      = (const float*)d_in[8];
  const float* out_proj_w = (const float*)d_in[9];
  const float* ln_g       = (const float*)d_in[10];
  const float* ln_b       = (const float*)d_in[11];
  const float* lin3_w     = (const float*)d_in[12];
  const float* lin3_b     = (const float*)d_in[13];
  const float* linsp_w    = (const float*)d_in[14];
  const float* linsp_b    = (const float*)d_in[15];
  const float* linres_w   = (const float*)d_in[16];
  const float* linres_b   = (const float*)d_in[17];
  float* out = (float*)d_out;

  char* ws = (char*)d_ws;
  const size_t MB = 1024 * 1024;
  unsigned short* w_in_bf     = (unsigned short*)(ws + 0);                     // 4 MB
  unsigned short* w_out_bf    = (unsigned short*)(ws + 4 * MB);                // 2 MB
  unsigned short* w_linsp_bf  = (unsigned short*)(ws + 6 * MB);                // 2 MB
  unsigned short* w_dt_bf     = (unsigned short*)(ws + 8 * MB);                // 128 KB
  unsigned short* xpT_bf      = (unsigned short*)(ws + 8 * MB + 128 * 1024);   // 128 KB
  float*          BC          = (float*)(ws + 8 * MB + 256 * 1024);            // 128 KB
  unsigned short* W_eff       = (unsigned short*)(ws + 9 * MB);                // 2 MB
  unsigned short* w_lin3_bf   = (unsigned short*)(ws + 11 * MB);               // 512 KB
  unsigned short* w_linres_bf = (unsigned short*)(ws + 11 * MB + 512 * 1024);  // 512 KB
  unsigned short* x_bf  = (unsigned short*)(ws + 16 * MB);  // 16 MB
  unsigned short* xz    = (unsigned short*)(ws + 32 * MB);  // 32 MB: [8192][2048] xs_pre|z -> delta|z -> Rt
  unsigned short* seg3  = (unsigned short*)(ws + 64 * MB);  // 16 MB: xs -> Yt
  unsigned short* seg4  = (unsigned short*)(ws + 80 * MB);  // 16 MB: y_gated

  dim3 blk(256);
  // 1: all casts fused (x + 6 weights)
  fused_cast<<<12864, blk, 0, stream>>>(x, in_proj_w, out_proj_w, linsp_w,
                                        dt_proj_w, lin3_w, linres_w,
                                        x_bf, w_in_bf, w_out_bf, w_linsp_bf,
                                        w_dt_bf, w_lin3_bf, w_linres_bf);
  // 2: transpose-cast x_proj rows 0..63
  transpose_cast_xp<<<256, blk, 0, stream>>>(x_proj_w, xpT_bf);
  // 3: W_eff = dt_proj_w @ x_proj_w[0:64]  (M=1024, N=1024, K=64)
  gemm_bf16_nt64<0, 0><<<dim3(8, 8), blk, 0, stream>>>(
      w_dt_bf, 64, xpT_bf, 64, nullptr, W_eff, 1024, 64);
  // 4: in_proj merged (N=2048) -> xz
  gemm_bf16_nt64<0, 0><<<dim3(16, 64), blk, 0, stream>>>(
      x_bf, 1024, w_in_bf, 1024, nullptr, xz, 2048, 1024);
  // 5: fused conv + silu -> xs (seg3) AND BC (fp32)
  conv_bc_fused<<<8192, blk, 0, stream>>>(xz, conv_w, conv_b, x_proj_w, seg3, BC);
  // 6: delta = softplus(xs . W_eff^T + dt_proj_b) -> xz cols 0-1023
  gemm_bf16_nt64<2, 1><<<dim3(8, 64), blk, 0, stream>>>(
      seg3, 1024, W_eff, 1024, dt_proj_b, xz, 2048, 1024);
  // 7: chunked scan -> y_gated (seg4)
  scan_chunked<<<dim3(16, 16), dim3(1024), 0, stream>>>(
      xz, xz + 1024, 2048, seg3, BC, A_log, D_ssm, seg4);
  // 8: merged batched GEMM: Yt -> seg3 (xs dead), Rt -> xz (delta/z dead)
  gemm_bat2_64<<<dim3(4, 8, 32), blk, 0, stream>>>(
      w_out_bf, w_linsp_bf, seg4, x_bf, linsp_b, seg3, xz);
  // 9: column LayerNorm on Yt
  ln_col<<<dim3(8, 16), blk, 0, stream>>>(seg3, ln_g, ln_b);
  // 10: fused final dual MFMA
  gemm_dual_mfma<<<dim3(8, 4, 16), blk, 0, stream>>>(
      w_lin3_bf, w_linres_bf, lin3_b, linres_b, seg3, xz, out);
}